// Round 1
// baseline (808.790 us; speedup 1.0000x reference)
//
#include <hip/hip_runtime.h>
#include <hip/hip_bf16.h>
#include <math.h>

// Mamba block forward, fp32 baseline.
// Shapes: B=2, L=1024, DIM=1024, DIM_INNER=2048, D_STATE=16, D_CONV=4, DT_RANK=64
// Pipeline:
//   xr[2048,4096]   = x[2048,1024] @ W_in[1024,4096]          (gemm_f32<0>)
//   u[2048,2048]    = silu(causal_dwconv(xr[:, :2048]) + cb)  (conv_silu)
//   xdbl[2048,96]   = u @ W_x[2048,96]                        (gemm_f32<0>)
//   delta[2048,2048]= softplus(xdbl[:,:64] @ W_dt + b_dt)     (gemm_f32<1>)
//   ys              = selective_scan(delta,u,B=xdbl[:,64:80],C=xdbl[:,80:96],A=-exp(A_log))
//   ys              = (ys + u*D) * silu(xr[:,2048:])          (gate, in-place)
//   out[2048,1024]  = ys @ W_out[2048,1024]                   (gemm_f32<0>)

#define TILE 64
#define BKK  16
#define LPAD 68   // TILE + 4 pad: keeps float4 LDS rows 16B-aligned, breaks bank conflicts

__device__ __forceinline__ float silu_f(float x) {
    return x / (1.f + expf(-x));
}

// C[M,N] = A[M,K] @ B[K,N]; MODE 1: C = softplus(C + bias[col])
// Grid: (ceil(N/64), M/64); block 256. M must be multiple of 64; K multiple of 16; N multiple of 4.
template<int MODE>
__global__ __launch_bounds__(256) void gemm_f32(
    const float* __restrict__ A, int lda,
    const float* __restrict__ B, int ldb,
    float* __restrict__ C, int ldc,
    const float* __restrict__ bias,
    int N, int K)
{
    __shared__ float As[BKK][LPAD];   // [k][m]
    __shared__ float Bs[BKK][LPAD];   // [k][n]
    const int tid = threadIdx.x;
    const int tx = tid & 15, ty = tid >> 4;
    const int row0 = blockIdx.y * TILE, col0 = blockIdx.x * TILE;

    const int arow = tid >> 2;          // 0..63
    const int acol = (tid & 3) << 2;    // 0,4,8,12
    const int brow = tid >> 4;          // 0..15
    const int bcol = (tid & 15) << 2;   // 0..60

    float acc[4][4] = {};

    for (int k0 = 0; k0 < K; k0 += BKK) {
        float4 av = *(const float4*)(A + (size_t)(row0 + arow) * lda + k0 + acol);
        As[acol + 0][arow] = av.x;
        As[acol + 1][arow] = av.y;
        As[acol + 2][arow] = av.z;
        As[acol + 3][arow] = av.w;
        float4 bv = make_float4(0.f, 0.f, 0.f, 0.f);
        if (col0 + bcol < N)
            bv = *(const float4*)(B + (size_t)(k0 + brow) * ldb + col0 + bcol);
        *(float4*)(&Bs[brow][bcol]) = bv;
        __syncthreads();
        #pragma unroll
        for (int k = 0; k < BKK; ++k) {
            float4 a4 = *(const float4*)(&As[k][ty << 2]);
            float4 b4 = *(const float4*)(&Bs[k][tx << 2]);
            float a[4] = {a4.x, a4.y, a4.z, a4.w};
            float bb[4] = {b4.x, b4.y, b4.z, b4.w};
            #pragma unroll
            for (int i = 0; i < 4; ++i)
                #pragma unroll
                for (int j = 0; j < 4; ++j)
                    acc[i][j] = fmaf(a[i], bb[j], acc[i][j]);
        }
        __syncthreads();
    }
    #pragma unroll
    for (int i = 0; i < 4; ++i) {
        int r = row0 + (ty << 2) + i;
        #pragma unroll
        for (int j = 0; j < 4; ++j) {
            int c = col0 + (tx << 2) + j;
            if (c < N) {
                float v = acc[i][j];
                if (MODE == 1) {
                    v += bias[c];
                    v = (v > 20.f) ? v : log1pf(expf(v));
                }
                C[(size_t)r * ldc + c] = v;
            }
        }
    }
}

// u[b,l,d] = silu( sum_{w=0..3} xr[b, l+w-3, d] * conv_w[d,w] + conv_b[d] )
__global__ __launch_bounds__(256) void conv_silu(
    const float* __restrict__ xr,      // [2048][4096], u-half = cols 0..2047
    const float* __restrict__ conv_w,  // [2048][4]
    const float* __restrict__ conv_b,  // [2048]
    float* __restrict__ u)             // [2048][2048]
{
    int idx = blockIdx.x * 256 + threadIdx.x;   // 0..4194303
    int d = idx & 2047;
    int r = idx >> 11;         // b*1024 + l
    int l = r & 1023;
    int b = r >> 10;
    float acc = conv_b[d];
    const float* wp = conv_w + d * 4;
    #pragma unroll
    for (int w = 0; w < 4; ++w) {
        int ls = l + w - 3;
        if (ls >= 0)
            acc = fmaf(xr[((size_t)((b << 10) + ls) << 12) + d], wp[w], acc);
    }
    u[idx] = silu_f(acc);
}

// Selective scan. Block: 256 threads = 16 channels x 16 states, one batch.
// Grid: (2048/16, 2). Thread (ch, n) carries h[d0+ch][n] across L.
#define LCH 32
__global__ __launch_bounds__(256) void scan_kernel(
    const float* __restrict__ delta,  // [2048][2048]
    const float* __restrict__ u,      // [2048][2048]
    const float* __restrict__ xdbl,   // [2048][96]: [:,64:80]=B, [:,80:96]=C
    const float* __restrict__ A_log,  // [2048][16]
    float* __restrict__ ys)           // [2048][2048]
{
    __shared__ float ds_[LCH][16];
    __shared__ float us_[LCH][16];
    __shared__ float bs_[LCH][16];
    __shared__ float cs_[LCH][16];
    const int tid = threadIdx.x;
    const int d0 = blockIdx.x * 16;
    const int b  = blockIdx.y;
    const int ch = tid >> 4;
    const int n  = tid & 15;
    const float Aval = -expf(A_log[(d0 + ch) * 16 + n]);
    float h = 0.f;
    for (int l0 = 0; l0 < 1024; l0 += LCH) {
        __syncthreads();   // protect LDS from previous chunk's readers
        for (int e = tid; e < LCH * 16; e += 256) {
            int li = e >> 4, c = e & 15;
            size_t row = (size_t)(b << 10) + l0 + li;
            ds_[li][c] = delta[(row << 11) + d0 + c];
            us_[li][c] = u[(row << 11) + d0 + c];
            bs_[li][c] = xdbl[row * 96 + 64 + c];
            cs_[li][c] = xdbl[row * 96 + 80 + c];
        }
        __syncthreads();
        for (int li = 0; li < LCH; ++li) {
            float dlt = ds_[li][ch];
            float uu  = us_[li][ch];
            h = expf(dlt * Aval) * h + dlt * bs_[li][n] * uu;
            float p = h * cs_[li][n];
            p += __shfl_xor(p, 8, 16);
            p += __shfl_xor(p, 4, 16);
            p += __shfl_xor(p, 2, 16);
            p += __shfl_xor(p, 1, 16);
            if (n == 0)
                ys[(((size_t)(b << 10) + l0 + li) << 11) + d0 + ch] = p;
        }
    }
}

// ys = (ys + u*D) * silu(res), res = xr[:, 2048:]
__global__ __launch_bounds__(256) void gate_kernel(
    float* __restrict__ ys,
    const float* __restrict__ u,
    const float* __restrict__ xr,
    const float* __restrict__ Dv)
{
    int idx = blockIdx.x * 256 + threadIdx.x;
    int d = idx & 2047;
    int r = idx >> 11;
    float resv = xr[((size_t)r << 12) + 2048 + d];
    ys[idx] = (ys[idx] + u[idx] * Dv[d]) * silu_f(resv);
}

extern "C" void kernel_launch(void* const* d_in, const int* in_sizes, int n_in,
                              void* d_out, int out_size, void* d_ws, size_t ws_size,
                              hipStream_t stream)
{
    const float* x      = (const float*)d_in[0];
    const float* W_in   = (const float*)d_in[1];
    const float* conv_w = (const float*)d_in[2];
    const float* conv_b = (const float*)d_in[3];
    const float* W_x    = (const float*)d_in[4];
    const float* W_dt   = (const float*)d_in[5];
    const float* b_dt   = (const float*)d_in[6];
    const float* A_log  = (const float*)d_in[7];
    const float* Dv     = (const float*)d_in[8];
    const float* W_out  = (const float*)d_in[9];
    float* out = (float*)d_out;

    float* ws    = (float*)d_ws;
    float* xr    = ws;                              // 2048*4096 = 8388608
    float* u     = xr + (size_t)2048 * 4096;        // 2048*2048 = 4194304
    float* xdbl  = u + (size_t)2048 * 2048;         // 2048*96   = 196608
    float* delta = xdbl + (size_t)2048 * 96;        // 2048*2048 = 4194304
    float* ys    = delta + (size_t)2048 * 2048;     // 2048*2048 = 4194304
    // total ~84.7 MB of d_ws

    // 1. xr = x @ W_in            [2048,1024] @ [1024,4096]
    gemm_f32<0><<<dim3(64, 32), 256, 0, stream>>>(x, 1024, W_in, 4096, xr, 4096, nullptr, 4096, 1024);
    // 2. u = silu(causal depthwise conv(xr[:, :2048]))
    conv_silu<<<16384, 256, 0, stream>>>(xr, conv_w, conv_b, u);
    // 3. xdbl = u @ W_x           [2048,2048] @ [2048,96]
    gemm_f32<0><<<dim3(2, 32), 256, 0, stream>>>(u, 2048, W_x, 96, xdbl, 96, nullptr, 96, 2048);
    // 4. delta = softplus(xdbl[:, :64] @ W_dt + b_dt)   [2048,64] @ [64,2048]
    gemm_f32<1><<<dim3(32, 32), 256, 0, stream>>>(xdbl, 96, W_dt, 2048, delta, 2048, b_dt, 2048, 64);
    // 5. selective scan
    scan_kernel<<<dim3(128, 2), 256, 0, stream>>>(delta, u, xdbl, A_log, ys);
    // 6. gate (in-place on ys)
    gate_kernel<<<16384, 256, 0, stream>>>(ys, u, xr, Dv);
    // 7. out = ys @ W_out         [2048,2048] @ [2048,1024]
    gemm_f32<0><<<dim3(16, 32), 256, 0, stream>>>(ys, 2048, W_out, 1024, out, 1024, nullptr, 1024, 2048);
}

// Round 3
// 607.799 us; speedup vs baseline: 1.3307x; 1.3307x over previous
//
#include <hip/hip_runtime.h>
#include <hip/hip_bf16.h>
#include <math.h>

// Mamba block forward. fp32 GEMMs (MFMA conversion pending), ILP-restructured scan.
// Shapes: B=2, L=1024, DIM=1024, DIM_INNER=2048, D_STATE=16, D_CONV=4, DT_RANK=64

#define TILE 64
#define BKK  16
#define LPAD 68   // TILE + 4 pad

__device__ __forceinline__ float silu_f(float x) {
    return x / (1.f + __expf(-x));
}

// C[M,N] = A[M,K] @ B[K,N]; MODE 1: C = softplus(C + bias[col])
template<int MODE>
__global__ __launch_bounds__(256) void gemm_f32(
    const float* __restrict__ A, int lda,
    const float* __restrict__ B, int ldb,
    float* __restrict__ C, int ldc,
    const float* __restrict__ bias,
    int N, int K)
{
    __shared__ float As[BKK][LPAD];   // [k][m]
    __shared__ float Bs[BKK][LPAD];   // [k][n]
    const int tid = threadIdx.x;
    const int tx = tid & 15, ty = tid >> 4;
    const int row0 = blockIdx.y * TILE, col0 = blockIdx.x * TILE;

    const int arow = tid >> 2;
    const int acol = (tid & 3) << 2;
    const int brow = tid >> 4;
    const int bcol = (tid & 15) << 2;

    float acc[4][4] = {};

    for (int k0 = 0; k0 < K; k0 += BKK) {
        float4 av = *(const float4*)(A + (size_t)(row0 + arow) * lda + k0 + acol);
        As[acol + 0][arow] = av.x;
        As[acol + 1][arow] = av.y;
        As[acol + 2][arow] = av.z;
        As[acol + 3][arow] = av.w;
        float4 bv = make_float4(0.f, 0.f, 0.f, 0.f);
        if (col0 + bcol < N)
            bv = *(const float4*)(B + (size_t)(k0 + brow) * ldb + col0 + bcol);
        *(float4*)(&Bs[brow][bcol]) = bv;
        __syncthreads();
        #pragma unroll
        for (int k = 0; k < BKK; ++k) {
            float4 a4 = *(const float4*)(&As[k][ty << 2]);
            float4 b4 = *(const float4*)(&Bs[k][tx << 2]);
            float a[4] = {a4.x, a4.y, a4.z, a4.w};
            float bb[4] = {b4.x, b4.y, b4.z, b4.w};
            #pragma unroll
            for (int i = 0; i < 4; ++i)
                #pragma unroll
                for (int j = 0; j < 4; ++j)
                    acc[i][j] = fmaf(a[i], bb[j], acc[i][j]);
        }
        __syncthreads();
    }
    #pragma unroll
    for (int i = 0; i < 4; ++i) {
        int r = row0 + (ty << 2) + i;
        #pragma unroll
        for (int j = 0; j < 4; ++j) {
            int c = col0 + (tx << 2) + j;
            if (c < N) {
                float v = acc[i][j];
                if (MODE == 1) {
                    v += bias[c];
                    v = (v > 20.f) ? v : log1pf(expf(v));
                }
                C[(size_t)r * ldc + c] = v;
            }
        }
    }
}

// u[b,l,d] = silu( sum_{w} xr[b, l+w-3, d] * conv_w[d,w] + conv_b[d] )
__global__ __launch_bounds__(256) void conv_silu(
    const float* __restrict__ xr,
    const float* __restrict__ conv_w,
    const float* __restrict__ conv_b,
    float* __restrict__ u)
{
    int idx = blockIdx.x * 256 + threadIdx.x;
    int d = idx & 2047;
    int r = idx >> 11;
    int l = r & 1023;
    int b = r >> 10;
    float acc = conv_b[d];
    const float* wp = conv_w + d * 4;
    #pragma unroll
    for (int w = 0; w < 4; ++w) {
        int ls = l + w - 3;
        if (ls >= 0)
            acc = fmaf(xr[((size_t)((b << 10) + ls) << 12) + d], wp[w], acc);
    }
    u[idx] = silu_f(acc);
}

// ---------------- selective scan, ILP-batched, gate fused ----------------
// Block: 256 threads = 16 channels x 16 states. Grid (128, 2).
// Thread (ch, n) carries h[d0+ch][n]. Per 16-step chunk:
//   phase1: compute e=exp(dlt*A), f=dlt*B*u, c (independent, ILP)
//   phase2: serial h = e*h + f (one 4-cycle FMA per step); p = h*c
//   phase3: 16-lane DPP reduce of p; lane n keeps timestep l0+n's sum
//   epilogue: all 64 lanes apply skip + gate and store one element each.
// LDS double-buffered; global loads issued before compute, ds_write after.
#define SCAN_T 16

#define DPP_ADD(v, ctrl) ((v) + __int_as_float(__builtin_amdgcn_update_dpp( \
        0, __float_as_int(v), (ctrl), 0xF, 0xF, true)))

__global__ __launch_bounds__(256) void scan_kernel(
    const float* __restrict__ delta,  // [2048][2048]
    const float* __restrict__ u,      // [2048][2048]
    const float* __restrict__ xdbl,   // [2048][96]: [:,64:80]=B, [:,80:96]=C
    const float* __restrict__ A_log,  // [2048][16]
    const float* __restrict__ xr,     // [2048][4096], res = cols 2048..4095
    const float* __restrict__ Dv,     // [2048]
    float* __restrict__ ys)           // [2048][2048]
{
    __shared__ float2 du[2][SCAN_T][17];  // (delta, u)  indexed [li][channel]
    __shared__ float2 bc[2][SCAN_T][17];  // (B, C)      indexed [li][state n]
    __shared__ float  rs[2][SCAN_T][17];  // res         indexed [li][channel]

    const int tid = threadIdx.x;
    const int d0 = blockIdx.x * 16;
    const int b  = blockIdx.y;
    const int ch = tid >> 4;
    const int n  = tid & 15;

    const float Aval = -__expf(A_log[(d0 + ch) * 16 + n]);
    const float Dval = Dv[d0 + ch];

    const int sli = tid >> 4, sc = tid & 15;  // cooperative staging indices

    float g_d, g_u, g_b, g_c, g_r;
    {   // prologue: chunk 0
        size_t row = (size_t)(b << 10) + sli;
        g_d = delta[(row << 11) + d0 + sc];
        g_u = u[(row << 11) + d0 + sc];
        g_b = xdbl[row * 96 + 64 + sc];
        g_c = xdbl[row * 96 + 80 + sc];
        g_r = xr[(row << 12) + 2048 + d0 + sc];
    }
    du[0][sli][sc] = make_float2(g_d, g_u);
    bc[0][sli][sc] = make_float2(g_b, g_c);
    rs[0][sli][sc] = g_r;
    __syncthreads();

    float h = 0.f;
    int cb = 0;
    for (int c = 0; c < 1024 / SCAN_T; ++c) {
        const int l0 = c * SCAN_T;
        const bool more = (c + 1) < 1024 / SCAN_T;
        if (more) {   // issue next chunk's global loads early (latency hides under compute)
            size_t row = (size_t)(b << 10) + l0 + SCAN_T + sli;
            g_d = delta[(row << 11) + d0 + sc];
            g_u = u[(row << 11) + d0 + sc];
            g_b = xdbl[row * 96 + 64 + sc];
            g_c = xdbl[row * 96 + 80 + sc];
            g_r = xr[(row << 12) + 2048 + d0 + sc];
        }
        // phase 1: h-independent per-step quantities, full ILP
        float e_[SCAN_T], f_[SCAN_T], c_[SCAN_T];
        #pragma unroll
        for (int li = 0; li < SCAN_T; ++li) {
            float2 duv = du[cb][li][ch];
            float2 bcv = bc[cb][li][n];
            e_[li] = __expf(duv.x * Aval);
            f_[li] = duv.x * bcv.x * duv.y;
            c_[li] = bcv.y;
        }
        // phase 2+3: serial h chain; DPP tree-reduce over the 16 state lanes
        float mysum = 0.f;
        #pragma unroll
        for (int li = 0; li < SCAN_T; ++li) {
            h = fmaf(e_[li], h, f_[li]);
            float pv = h * c_[li];
            pv = DPP_ADD(pv, 0xB1);   // quad_perm xor1
            pv = DPP_ADD(pv, 0x4E);   // quad_perm xor2
            pv = DPP_ADD(pv, 0x141);  // row_half_mirror (8-sum)
            pv = DPP_ADD(pv, 0x140);  // row_mirror (16-sum, all lanes)
            mysum = (n == li) ? pv : mysum;
        }
        // epilogue: lane (ch,n) finishes timestep l0+n for channel d0+ch
        {
            float2 duv = du[cb][n][ch];
            float resv = rs[cb][n][ch];
            float outv = (mysum + duv.y * Dval) * silu_f(resv);
            ys[((size_t)((b << 10) + l0 + n) << 11) + d0 + ch] = outv;
        }
        if (more) {   // write next chunk into the other buffer
            du[cb ^ 1][sli][sc] = make_float2(g_d, g_u);
            bc[cb ^ 1][sli][sc] = make_float2(g_b, g_c);
            rs[cb ^ 1][sli][sc] = g_r;
        }
        __syncthreads();
        cb ^= 1;
    }
}

extern "C" void kernel_launch(void* const* d_in, const int* in_sizes, int n_in,
                              void* d_out, int out_size, void* d_ws, size_t ws_size,
                              hipStream_t stream)
{
    const float* x      = (const float*)d_in[0];
    const float* W_in   = (const float*)d_in[1];
    const float* conv_w = (const float*)d_in[2];
    const float* conv_b = (const float*)d_in[3];
    const float* W_x    = (const float*)d_in[4];
    const float* W_dt   = (const float*)d_in[5];
    const float* b_dt   = (const float*)d_in[6];
    const float* A_log  = (const float*)d_in[7];
    const float* Dv     = (const float*)d_in[8];
    const float* W_out  = (const float*)d_in[9];
    float* out = (float*)d_out;

    float* ws    = (float*)d_ws;
    float* xr    = ws;                              // 2048*4096
    float* u     = xr + (size_t)2048 * 4096;        // 2048*2048
    float* xdbl  = u + (size_t)2048 * 2048;         // 2048*96
    float* delta = xdbl + (size_t)2048 * 96;        // 2048*2048
    float* ys    = delta + (size_t)2048 * 2048;     // 2048*2048

    // 1. xr = x @ W_in            [2048,1024] @ [1024,4096]
    gemm_f32<0><<<dim3(64, 32), 256, 0, stream>>>(x, 1024, W_in, 4096, xr, 4096, nullptr, 4096, 1024);
    // 2. u = silu(causal depthwise conv(xr[:, :2048]))
    conv_silu<<<16384, 256, 0, stream>>>(xr, conv_w, conv_b, u);
    // 3. xdbl = u @ W_x           [2048,2048] @ [2048,96]
    gemm_f32<0><<<dim3(2, 32), 256, 0, stream>>>(u, 2048, W_x, 96, xdbl, 96, nullptr, 96, 2048);
    // 4. delta = softplus(xdbl[:, :64] @ W_dt + b_dt)   [2048,64] @ [64,2048]
    gemm_f32<1><<<dim3(32, 32), 256, 0, stream>>>(xdbl, 96, W_dt, 2048, delta, 2048, b_dt, 2048, 64);
    // 5. selective scan + skip + gate (fused)
    scan_kernel<<<dim3(128, 2), 256, 0, stream>>>(delta, u, xdbl, A_log, xr, Dv, ys);
    // 6. out = ys @ W_out         [2048,2048] @ [2048,1024]
    gemm_f32<0><<<dim3(16, 32), 256, 0, stream>>>(ys, 2048, W_out, 1024, out, 1024, nullptr, 1024, 2048);
}

// Round 4
// 327.563 us; speedup vs baseline: 2.4691x; 1.8555x over previous
//
#include <hip/hip_runtime.h>
#include <hip/hip_bf16.h>
#include <math.h>

// Mamba block forward. Big GEMMs in bf16 MFMA (m97 structure), scan ILP-batched.
// Shapes: B=2, L=1024, DIM=1024, DIM_INNER=2048, D_STATE=16, D_CONV=4, DT_RANK=64

#define TILE 64
#define BKK  16
#define LPAD 68

__device__ __forceinline__ float silu_f(float x) {
    return x / (1.f + __expf(-x));
}

__device__ __forceinline__ unsigned short f2bf(float f) {
    __hip_bfloat16 h = __float2bfloat16(f);
    return *(unsigned short*)&h;
}

// ---------------- bf16 MFMA GEMM: C[M,N] = A[M,K] @ BT[N,K]^T ----------------
// 128x128 tile, 4 waves, each wave owns 64x64 (4x4 frags of 16x16x32).
// M%128==0, N%128==0, K%32==0. A,BT row-major bf16 (ushort bits), C fp32.
typedef __attribute__((ext_vector_type(8))) short short8v;   // 8 bf16
typedef __attribute__((ext_vector_type(4))) float f32x4;

__device__ __forceinline__ void gload16(const void* g, void* lds) {
    __builtin_amdgcn_global_load_lds(
        (const __attribute__((address_space(1))) unsigned int*)g,
        (__attribute__((address_space(3))) unsigned int*)lds, 16, 0, 0);
}

__global__ __launch_bounds__(256) void gemm_bf16(
    const unsigned short* __restrict__ A,   // [M][K]
    const unsigned short* __restrict__ BT,  // [N][K]
    float* __restrict__ C,
    int M, int N, int K)
{
    __shared__ unsigned short As[128 * 32];   // [row][k] 8KB
    __shared__ unsigned short Bs[128 * 32];   // [col][k] 8KB
    const int tid  = threadIdx.x;
    const int wid  = tid >> 6;
    const int lane = tid & 63;
    const int wr = wid >> 1, wc = wid & 1;
    const int row0 = blockIdx.y * 128, col0 = blockIdx.x * 128;

    f32x4 acc[4][4] = {};

    const int srow = lane >> 2;          // 0..15 within chunk
    const int scol = (lane & 3) * 8;     // ushort offset of 16B piece

    for (int k0 = 0; k0 < K; k0 += 32) {
        #pragma unroll
        for (int c = 0; c < 2; ++c) {
            int chunk = wid * 2 + c;     // 0..7, 16 rows each
            gload16(A  + (size_t)(row0 + chunk * 16 + srow) * K + k0 + scol,
                    (void*)(As + chunk * 512));
            gload16(BT + (size_t)(col0 + chunk * 16 + srow) * K + k0 + scol,
                    (void*)(Bs + chunk * 512));
        }
        __syncthreads();
        short8v a[4], b[4];
        #pragma unroll
        for (int i = 0; i < 4; ++i)
            a[i] = *(const short8v*)&As[(wr * 64 + i * 16 + (lane & 15)) * 32 + (lane >> 4) * 8];
        #pragma unroll
        for (int j = 0; j < 4; ++j)
            b[j] = *(const short8v*)&Bs[(wc * 64 + j * 16 + (lane & 15)) * 32 + (lane >> 4) * 8];
        #pragma unroll
        for (int i = 0; i < 4; ++i)
            #pragma unroll
            for (int j = 0; j < 4; ++j)
                acc[i][j] = __builtin_amdgcn_mfma_f32_16x16x32_bf16(a[i], b[j], acc[i][j], 0, 0, 0);
        __syncthreads();
    }

    #pragma unroll
    for (int i = 0; i < 4; ++i) {
        int rbase = row0 + wr * 64 + i * 16 + (lane >> 4) * 4;
        #pragma unroll
        for (int j = 0; j < 4; ++j) {
            int cc = col0 + wc * 64 + j * 16 + (lane & 15);
            #pragma unroll
            for (int r = 0; r < 4; ++r)
                C[(size_t)(rbase + r) * N + cc] = acc[i][j][r];
        }
    }
}

// ---------------- conversions ----------------
// fp32 -> bf16 elementwise, 4 elems/thread
__global__ __launch_bounds__(256) void to_bf16(
    const float* __restrict__ src, unsigned short* __restrict__ dst, int n4)
{
    int i = blockIdx.x * 256 + threadIdx.x;
    if (i >= n4) return;
    float4 v = *(const float4*)(src + (size_t)i * 4);
    ushort4 o;
    o.x = f2bf(v.x); o.y = f2bf(v.y); o.z = f2bf(v.z); o.w = f2bf(v.w);
    *(ushort4*)(dst + (size_t)i * 4) = o;
}

// W[K][N] fp32 -> WT[N][K] bf16, 64x64 LDS tile. K%64==0, N%64==0.
__global__ __launch_bounds__(256) void transpose_to_bf16(
    const float* __restrict__ W, unsigned short* __restrict__ WT, int K, int N)
{
    __shared__ float t[64][65];
    const int tx = threadIdx.x & 63, ty = threadIdx.x >> 6;   // ty 0..3
    const int bk = blockIdx.y * 64, bn = blockIdx.x * 64;
    #pragma unroll
    for (int s = 0; s < 16; ++s)
        t[ty + 4 * s][tx] = W[(size_t)(bk + ty + 4 * s) * N + bn + tx];
    __syncthreads();
    #pragma unroll
    for (int s = 0; s < 16; ++s)
        WT[(size_t)(bn + ty + 4 * s) * K + bk + tx] = f2bf(t[tx][ty + 4 * s]);
}

// ---------------- fp32 GEMM (small mid GEMMs) ----------------
template<int MODE>
__global__ __launch_bounds__(256) void gemm_f32(
    const float* __restrict__ A, int lda,
    const float* __restrict__ B, int ldb,
    float* __restrict__ C, int ldc,
    const float* __restrict__ bias,
    int N, int K)
{
    __shared__ float As[BKK][LPAD];
    __shared__ float Bs[BKK][LPAD];
    const int tid = threadIdx.x;
    const int tx = tid & 15, ty = tid >> 4;
    const int row0 = blockIdx.y * TILE, col0 = blockIdx.x * TILE;

    const int arow = tid >> 2;
    const int acol = (tid & 3) << 2;
    const int brow = tid >> 4;
    const int bcol = (tid & 15) << 2;

    float acc[4][4] = {};

    for (int k0 = 0; k0 < K; k0 += BKK) {
        float4 av = *(const float4*)(A + (size_t)(row0 + arow) * lda + k0 + acol);
        As[acol + 0][arow] = av.x;
        As[acol + 1][arow] = av.y;
        As[acol + 2][arow] = av.z;
        As[acol + 3][arow] = av.w;
        float4 bv = make_float4(0.f, 0.f, 0.f, 0.f);
        if (col0 + bcol < N)
            bv = *(const float4*)(B + (size_t)(k0 + brow) * ldb + col0 + bcol);
        *(float4*)(&Bs[brow][bcol]) = bv;
        __syncthreads();
        #pragma unroll
        for (int k = 0; k < BKK; ++k) {
            float4 a4 = *(const float4*)(&As[k][ty << 2]);
            float4 b4 = *(const float4*)(&Bs[k][tx << 2]);
            float a[4] = {a4.x, a4.y, a4.z, a4.w};
            float bb[4] = {b4.x, b4.y, b4.z, b4.w};
            #pragma unroll
            for (int i = 0; i < 4; ++i)
                #pragma unroll
                for (int j = 0; j < 4; ++j)
                    acc[i][j] = fmaf(a[i], bb[j], acc[i][j]);
        }
        __syncthreads();
    }
    #pragma unroll
    for (int i = 0; i < 4; ++i) {
        int r = row0 + (ty << 2) + i;
        #pragma unroll
        for (int j = 0; j < 4; ++j) {
            int c = col0 + (tx << 2) + j;
            if (c < N) {
                float v = acc[i][j];
                if (MODE == 1) {
                    v += bias[c];
                    v = (v > 20.f) ? v : log1pf(expf(v));
                }
                C[(size_t)r * ldc + c] = v;
            }
        }
    }
}

// u = silu(causal depthwise conv(xr[:, :2048]) + conv_b)
__global__ __launch_bounds__(256) void conv_silu(
    const float* __restrict__ xr,
    const float* __restrict__ conv_w,
    const float* __restrict__ conv_b,
    float* __restrict__ u)
{
    int idx = blockIdx.x * 256 + threadIdx.x;
    int d = idx & 2047;
    int r = idx >> 11;
    int l = r & 1023;
    int b = r >> 10;
    float acc = conv_b[d];
    const float* wp = conv_w + d * 4;
    #pragma unroll
    for (int w = 0; w < 4; ++w) {
        int ls = l + w - 3;
        if (ls >= 0)
            acc = fmaf(xr[((size_t)((b << 10) + ls) << 12) + d], wp[w], acc);
    }
    u[idx] = silu_f(acc);
}

// ---------------- selective scan (ILP-batched, gate fused, bf16 out) --------
#define SCAN_T 16

#define DPP_ADD(v, ctrl) ((v) + __int_as_float(__builtin_amdgcn_update_dpp( \
        0, __float_as_int(v), (ctrl), 0xF, 0xF, true)))

__global__ __launch_bounds__(256) void scan_kernel(
    const float* __restrict__ delta,  // [2048][2048]
    const float* __restrict__ u,      // [2048][2048]
    const float* __restrict__ xdbl,   // [2048][96]: [:,64:80]=B, [:,80:96]=C
    const float* __restrict__ A_log,  // [2048][16]
    const float* __restrict__ xr,     // [2048][4096], res = cols 2048..4095
    const float* __restrict__ Dv,     // [2048]
    unsigned short* __restrict__ ysb) // [2048][2048] bf16
{
    __shared__ float2 du[2][SCAN_T][17];
    __shared__ float2 bc[2][SCAN_T][17];
    __shared__ float  rs[2][SCAN_T][17];

    const int tid = threadIdx.x;
    const int d0 = blockIdx.x * 16;
    const int b  = blockIdx.y;
    const int ch = tid >> 4;
    const int n  = tid & 15;

    const float Aval = -__expf(A_log[(d0 + ch) * 16 + n]);
    const float Dval = Dv[d0 + ch];

    const int sli = tid >> 4, sc = tid & 15;

    float g_d, g_u, g_b, g_c, g_r;
    {
        size_t row = (size_t)(b << 10) + sli;
        g_d = delta[(row << 11) + d0 + sc];
        g_u = u[(row << 11) + d0 + sc];
        g_b = xdbl[row * 96 + 64 + sc];
        g_c = xdbl[row * 96 + 80 + sc];
        g_r = xr[(row << 12) + 2048 + d0 + sc];
    }
    du[0][sli][sc] = make_float2(g_d, g_u);
    bc[0][sli][sc] = make_float2(g_b, g_c);
    rs[0][sli][sc] = g_r;
    __syncthreads();

    float h = 0.f;
    int cb = 0;
    for (int c = 0; c < 1024 / SCAN_T; ++c) {
        const int l0 = c * SCAN_T;
        const bool more = (c + 1) < 1024 / SCAN_T;
        if (more) {
            size_t row = (size_t)(b << 10) + l0 + SCAN_T + sli;
            g_d = delta[(row << 11) + d0 + sc];
            g_u = u[(row << 11) + d0 + sc];
            g_b = xdbl[row * 96 + 64 + sc];
            g_c = xdbl[row * 96 + 80 + sc];
            g_r = xr[(row << 12) + 2048 + d0 + sc];
        }
        float e_[SCAN_T], f_[SCAN_T], c_[SCAN_T];
        #pragma unroll
        for (int li = 0; li < SCAN_T; ++li) {
            float2 duv = du[cb][li][ch];
            float2 bcv = bc[cb][li][n];
            e_[li] = __expf(duv.x * Aval);
            f_[li] = duv.x * bcv.x * duv.y;
            c_[li] = bcv.y;
        }
        float mysum = 0.f;
        #pragma unroll
        for (int li = 0; li < SCAN_T; ++li) {
            h = fmaf(e_[li], h, f_[li]);
            float pv = h * c_[li];
            pv = DPP_ADD(pv, 0xB1);
            pv = DPP_ADD(pv, 0x4E);
            pv = DPP_ADD(pv, 0x141);
            pv = DPP_ADD(pv, 0x140);
            mysum = (n == li) ? pv : mysum;
        }
        {
            float2 duv = du[cb][n][ch];
            float resv = rs[cb][n][ch];
            float outv = (mysum + duv.y * Dval) * silu_f(resv);
            ysb[((size_t)((b << 10) + l0 + n) << 11) + d0 + ch] = f2bf(outv);
        }
        if (more) {
            du[cb ^ 1][sli][sc] = make_float2(g_d, g_u);
            bc[cb ^ 1][sli][sc] = make_float2(g_b, g_c);
            rs[cb ^ 1][sli][sc] = g_r;
        }
        __syncthreads();
        cb ^= 1;
    }
}

extern "C" void kernel_launch(void* const* d_in, const int* in_sizes, int n_in,
                              void* d_out, int out_size, void* d_ws, size_t ws_size,
                              hipStream_t stream)
{
    const float* x      = (const float*)d_in[0];
    const float* W_in   = (const float*)d_in[1];
    const float* conv_w = (const float*)d_in[2];
    const float* conv_b = (const float*)d_in[3];
    const float* W_x    = (const float*)d_in[4];
    const float* W_dt   = (const float*)d_in[5];
    const float* b_dt   = (const float*)d_in[6];
    const float* A_log  = (const float*)d_in[7];
    const float* Dv     = (const float*)d_in[8];
    const float* W_out  = (const float*)d_in[9];
    float* out = (float*)d_out;

    float* ws    = (float*)d_ws;
    float* xr    = ws;                              // 8,388,608 f (32MB)
    float* u     = xr + (size_t)8388608;            // 4,194,304 f
    float* xdbl  = u + (size_t)4194304;             // 196,608 f
    float* delta = xdbl + (size_t)196608;           // 4,194,304 f
    unsigned short* bfr = (unsigned short*)(delta + (size_t)4194304);
    // phase 1 (until GEMM1 done): xb = bfr[0..2M), W_inT = bfr[2M..6.3M)
    unsigned short* xb    = bfr;
    unsigned short* W_inT = bfr + (size_t)2097152;
    // phase 2 (after GEMM1): ysb = bfr[0..4.2M), W_outT = bfr[4.2M..6.3M)
    unsigned short* ysb    = bfr;
    unsigned short* W_outT = bfr + (size_t)4194304;

    // 0. conversions for GEMM1
    to_bf16<<<2048, 256, 0, stream>>>(x, xb, 524288);
    transpose_to_bf16<<<dim3(64, 16), 256, 0, stream>>>(W_in, W_inT, 1024, 4096);
    // 1. xr = x @ W_in            [2048,1024] @ [1024,4096]  (bf16 MFMA)
    gemm_bf16<<<dim3(32, 16), 256, 0, stream>>>(xb, W_inT, xr, 2048, 4096, 1024);
    // 2. u = silu(causal depthwise conv(xr[:, :2048]))
    conv_silu<<<16384, 256, 0, stream>>>(xr, conv_w, conv_b, u);
    // 2b. W_out -> W_outT bf16 (after GEMM1: aliases W_inT tail)
    transpose_to_bf16<<<dim3(16, 32), 256, 0, stream>>>(W_out, W_outT, 2048, 1024);
    // 3. xdbl = u @ W_x           [2048,2048] @ [2048,96]
    gemm_f32<0><<<dim3(2, 32), 256, 0, stream>>>(u, 2048, W_x, 96, xdbl, 96, nullptr, 96, 2048);
    // 4. delta = softplus(xdbl[:, :64] @ W_dt + b_dt)
    gemm_f32<1><<<dim3(32, 32), 256, 0, stream>>>(xdbl, 96, W_dt, 2048, delta, 2048, b_dt, 2048, 64);
    // 5. selective scan + skip + gate, bf16 output (aliases xb — dead by now)
    scan_kernel<<<dim3(128, 2), 256, 0, stream>>>(delta, u, xdbl, A_log, xr, Dv, ysb);
    // 6. out = ys @ W_out         [2048,2048] @ [2048,1024]  (bf16 MFMA)
    gemm_bf16<<<dim3(8, 16), 256, 0, stream>>>(ysb, W_outT, out, 2048, 1024, 2048);
}

// Round 5
// 208.793 us; speedup vs baseline: 3.8736x; 1.5688x over previous
//
#include <hip/hip_runtime.h>
#include <hip/hip_bf16.h>
#include <math.h>

// Mamba block forward. All three big GEMMs in bf16 MFMA (m97 structure, split-K
// for skinny/low-parallelism shapes), scan ILP-batched with fused gate.
// Shapes: B=2, L=1024, DIM=1024, DIM_INNER=2048, D_STATE=16, D_CONV=4, DT_RANK=64

#define TILE 64
#define BKK  16
#define LPAD 68

__device__ __forceinline__ float silu_f(float x) {
    return x / (1.f + __expf(-x));
}

__device__ __forceinline__ unsigned short f2bf(float f) {
    __hip_bfloat16 h = __float2bfloat16(f);
    return *(unsigned short*)&h;
}

// ---------------- bf16 MFMA GEMM: C[M,N] = A[M,K] @ BT[N,K]^T ----------------
// 128x128 tile, 4 waves each owning 64x64 (4x4 frags of 16x16x32).
// blockIdx.z = K-split index; each split covers klen of K and writes
// C + z*M*N. M%128==0, N%128==0, klen%32==0.
typedef __attribute__((ext_vector_type(8))) short short8v;
typedef __attribute__((ext_vector_type(4))) float f32x4;

__device__ __forceinline__ void gload16(const void* g, void* lds) {
    __builtin_amdgcn_global_load_lds(
        (const __attribute__((address_space(1))) unsigned int*)g,
        (__attribute__((address_space(3))) unsigned int*)lds, 16, 0, 0);
}

__global__ __launch_bounds__(256) void gemm_bf16(
    const unsigned short* __restrict__ A,   // [M][K]
    const unsigned short* __restrict__ BT,  // [N][K]
    float* __restrict__ C,
    int M, int N, int K, int klen)
{
    __shared__ unsigned short As[128 * 32];
    __shared__ unsigned short Bs[128 * 32];
    const int tid  = threadIdx.x;
    const int wid  = tid >> 6;
    const int lane = tid & 63;
    const int wr = wid >> 1, wc = wid & 1;
    const int row0 = blockIdx.y * 128, col0 = blockIdx.x * 128;
    const int kbeg = blockIdx.z * klen;
    C += (size_t)blockIdx.z * M * N;

    f32x4 acc[4][4] = {};

    const int srow = lane >> 2;
    const int scol = (lane & 3) * 8;

    for (int k0 = kbeg; k0 < kbeg + klen; k0 += 32) {
        #pragma unroll
        for (int c = 0; c < 2; ++c) {
            int chunk = wid * 2 + c;
            gload16(A  + (size_t)(row0 + chunk * 16 + srow) * K + k0 + scol,
                    (void*)(As + chunk * 512));
            gload16(BT + (size_t)(col0 + chunk * 16 + srow) * K + k0 + scol,
                    (void*)(Bs + chunk * 512));
        }
        __syncthreads();
        short8v a[4], b[4];
        #pragma unroll
        for (int i = 0; i < 4; ++i)
            a[i] = *(const short8v*)&As[(wr * 64 + i * 16 + (lane & 15)) * 32 + (lane >> 4) * 8];
        #pragma unroll
        for (int j = 0; j < 4; ++j)
            b[j] = *(const short8v*)&Bs[(wc * 64 + j * 16 + (lane & 15)) * 32 + (lane >> 4) * 8];
        #pragma unroll
        for (int i = 0; i < 4; ++i)
            #pragma unroll
            for (int j = 0; j < 4; ++j)
                acc[i][j] = __builtin_amdgcn_mfma_f32_16x16x32_bf16(a[i], b[j], acc[i][j], 0, 0, 0);
        __syncthreads();
    }

    #pragma unroll
    for (int i = 0; i < 4; ++i) {
        int rbase = row0 + wr * 64 + i * 16 + (lane >> 4) * 4;
        #pragma unroll
        for (int j = 0; j < 4; ++j) {
            int cc = col0 + wc * 64 + j * 16 + (lane & 15);
            #pragma unroll
            for (int r = 0; r < 4; ++r)
                C[(size_t)(rbase + r) * N + cc] = acc[i][j][r];
        }
    }
}

// ---------------- conversions ----------------
__global__ __launch_bounds__(256) void to_bf16(
    const float* __restrict__ src, unsigned short* __restrict__ dst, int n4)
{
    int i = blockIdx.x * 256 + threadIdx.x;
    if (i >= n4) return;
    float4 v = *(const float4*)(src + (size_t)i * 4);
    ushort4 o;
    o.x = f2bf(v.x); o.y = f2bf(v.y); o.z = f2bf(v.z); o.w = f2bf(v.w);
    *(ushort4*)(dst + (size_t)i * 4) = o;
}

// W[K][N] fp32 -> WT[N][K] bf16, 64x64 LDS tile. K%64==0, N%64==0.
__global__ __launch_bounds__(256) void transpose_to_bf16(
    const float* __restrict__ W, unsigned short* __restrict__ WT, int K, int N)
{
    __shared__ float t[64][65];
    const int tx = threadIdx.x & 63, ty = threadIdx.x >> 6;
    const int bk = blockIdx.y * 64, bn = blockIdx.x * 64;
    #pragma unroll
    for (int s = 0; s < 16; ++s)
        t[ty + 4 * s][tx] = W[(size_t)(bk + ty + 4 * s) * N + bn + tx];
    __syncthreads();
    #pragma unroll
    for (int s = 0; s < 16; ++s)
        WT[(size_t)(bn + ty + 4 * s) * K + bk + tx] = f2bf(t[tx][ty + 4 * s]);
}

// W_x[2048][96] fp32 -> WT[128][2048] bf16, rows 96..127 zeroed.
__global__ __launch_bounds__(256) void transpose_wx(
    const float* __restrict__ Wx, unsigned short* __restrict__ WT)
{
    int idx = blockIdx.x * 256 + threadIdx.x;   // over 128*2048
    int k = idx & 2047, n = idx >> 11;
    float v = (n < 96) ? Wx[(size_t)k * 96 + n] : 0.f;
    WT[idx] = f2bf(v);
}

// xdbl_pad[2048][128] = sum over 16 split-K partials
__global__ __launch_bounds__(256) void reduce16(
    const float* __restrict__ P, float* __restrict__ dst)
{
    int i = blockIdx.x * 256 + threadIdx.x;   // float4 index, 65536 total
    const float4* P4 = (const float4*)P;
    float4 s = P4[i];
    #pragma unroll
    for (int k = 1; k < 16; ++k) {
        float4 v = P4[i + (size_t)k * 65536];
        s.x += v.x; s.y += v.y; s.z += v.z; s.w += v.w;
    }
    ((float4*)dst)[i] = s;
}

// out[2048][1024] = P[0] + P[1]
__global__ __launch_bounds__(256) void reduce2(
    const float* __restrict__ P, float* __restrict__ dst)
{
    int i = blockIdx.x * 256 + threadIdx.x;   // float4 index, 524288 total
    const float4* P4 = (const float4*)P;
    float4 a = P4[i], b = P4[i + 524288];
    a.x += b.x; a.y += b.y; a.z += b.z; a.w += b.w;
    ((float4*)dst)[i] = a;
}

// ---------------- fp32 GEMM (GEMM4 only) ----------------
template<int MODE>
__global__ __launch_bounds__(256) void gemm_f32(
    const float* __restrict__ A, int lda,
    const float* __restrict__ B, int ldb,
    float* __restrict__ C, int ldc,
    const float* __restrict__ bias,
    int N, int K)
{
    __shared__ float As[BKK][LPAD];
    __shared__ float Bs[BKK][LPAD];
    const int tid = threadIdx.x;
    const int tx = tid & 15, ty = tid >> 4;
    const int row0 = blockIdx.y * TILE, col0 = blockIdx.x * TILE;

    const int arow = tid >> 2;
    const int acol = (tid & 3) << 2;
    const int brow = tid >> 4;
    const int bcol = (tid & 15) << 2;

    float acc[4][4] = {};

    for (int k0 = 0; k0 < K; k0 += BKK) {
        float4 av = *(const float4*)(A + (size_t)(row0 + arow) * lda + k0 + acol);
        As[acol + 0][arow] = av.x;
        As[acol + 1][arow] = av.y;
        As[acol + 2][arow] = av.z;
        As[acol + 3][arow] = av.w;
        float4 bv = make_float4(0.f, 0.f, 0.f, 0.f);
        if (col0 + bcol < N)
            bv = *(const float4*)(B + (size_t)(k0 + brow) * ldb + col0 + bcol);
        *(float4*)(&Bs[brow][bcol]) = bv;
        __syncthreads();
        #pragma unroll
        for (int k = 0; k < BKK; ++k) {
            float4 a4 = *(const float4*)(&As[k][ty << 2]);
            float4 b4 = *(const float4*)(&Bs[k][tx << 2]);
            float a[4] = {a4.x, a4.y, a4.z, a4.w};
            float bb[4] = {b4.x, b4.y, b4.z, b4.w};
            #pragma unroll
            for (int i = 0; i < 4; ++i)
                #pragma unroll
                for (int j = 0; j < 4; ++j)
                    acc[i][j] = fmaf(a[i], bb[j], acc[i][j]);
        }
        __syncthreads();
    }
    #pragma unroll
    for (int i = 0; i < 4; ++i) {
        int r = row0 + (ty << 2) + i;
        #pragma unroll
        for (int j = 0; j < 4; ++j) {
            int c = col0 + (tx << 2) + j;
            if (c < N) {
                float v = acc[i][j];
                if (MODE == 1) {
                    v += bias[c];
                    v = (v > 20.f) ? v : log1pf(expf(v));
                }
                C[(size_t)r * ldc + c] = v;
            }
        }
    }
}

// u = silu(causal depthwise conv(xr[:, :2048]) + conv_b); also emits bf16 copy
__global__ __launch_bounds__(256) void conv_silu(
    const float* __restrict__ xr,
    const float* __restrict__ conv_w,
    const float* __restrict__ conv_b,
    float* __restrict__ u,
    unsigned short* __restrict__ ub)
{
    int idx = blockIdx.x * 256 + threadIdx.x;
    int d = idx & 2047;
    int r = idx >> 11;
    int l = r & 1023;
    int b = r >> 10;
    float acc = conv_b[d];
    const float* wp = conv_w + d * 4;
    #pragma unroll
    for (int w = 0; w < 4; ++w) {
        int ls = l + w - 3;
        if (ls >= 0)
            acc = fmaf(xr[((size_t)((b << 10) + ls) << 12) + d], wp[w], acc);
    }
    float uv = silu_f(acc);
    u[idx] = uv;
    ub[idx] = f2bf(uv);
}

// ---------------- selective scan (ILP-batched, gate fused, bf16 out) --------
#define SCAN_T 16

#define DPP_ADD(v, ctrl) ((v) + __int_as_float(__builtin_amdgcn_update_dpp( \
        0, __float_as_int(v), (ctrl), 0xF, 0xF, true)))

__global__ __launch_bounds__(256) void scan_kernel(
    const float* __restrict__ delta,  // [2048][2048]
    const float* __restrict__ u,      // [2048][2048]
    const float* __restrict__ xdbl,   // [2048][128]: [:,64:80]=B, [:,80:96]=C
    const float* __restrict__ A_log,  // [2048][16]
    const float* __restrict__ xr,     // [2048][4096], res = cols 2048..4095
    const float* __restrict__ Dv,     // [2048]
    unsigned short* __restrict__ ysb) // [2048][2048] bf16
{
    __shared__ float2 du[2][SCAN_T][17];
    __shared__ float2 bc[2][SCAN_T][17];
    __shared__ float  rs[2][SCAN_T][17];

    const int tid = threadIdx.x;
    const int d0 = blockIdx.x * 16;
    const int b  = blockIdx.y;
    const int ch = tid >> 4;
    const int n  = tid & 15;

    const float Aval = -__expf(A_log[(d0 + ch) * 16 + n]);
    const float Dval = Dv[d0 + ch];

    const int sli = tid >> 4, sc = tid & 15;

    float g_d, g_u, g_b, g_c, g_r;
    {
        size_t row = (size_t)(b << 10) + sli;
        g_d = delta[(row << 11) + d0 + sc];
        g_u = u[(row << 11) + d0 + sc];
        g_b = xdbl[(row << 7) + 64 + sc];
        g_c = xdbl[(row << 7) + 80 + sc];
        g_r = xr[(row << 12) + 2048 + d0 + sc];
    }
    du[0][sli][sc] = make_float2(g_d, g_u);
    bc[0][sli][sc] = make_float2(g_b, g_c);
    rs[0][sli][sc] = g_r;
    __syncthreads();

    float h = 0.f;
    int cb = 0;
    for (int c = 0; c < 1024 / SCAN_T; ++c) {
        const int l0 = c * SCAN_T;
        const bool more = (c + 1) < 1024 / SCAN_T;
        if (more) {
            size_t row = (size_t)(b << 10) + l0 + SCAN_T + sli;
            g_d = delta[(row << 11) + d0 + sc];
            g_u = u[(row << 11) + d0 + sc];
            g_b = xdbl[(row << 7) + 64 + sc];
            g_c = xdbl[(row << 7) + 80 + sc];
            g_r = xr[(row << 12) + 2048 + d0 + sc];
        }
        float e_[SCAN_T], f_[SCAN_T], c_[SCAN_T];
        #pragma unroll
        for (int li = 0; li < SCAN_T; ++li) {
            float2 duv = du[cb][li][ch];
            float2 bcv = bc[cb][li][n];
            e_[li] = __expf(duv.x * Aval);
            f_[li] = duv.x * bcv.x * duv.y;
            c_[li] = bcv.y;
        }
        float mysum = 0.f;
        #pragma unroll
        for (int li = 0; li < SCAN_T; ++li) {
            h = fmaf(e_[li], h, f_[li]);
            float pv = h * c_[li];
            pv = DPP_ADD(pv, 0xB1);
            pv = DPP_ADD(pv, 0x4E);
            pv = DPP_ADD(pv, 0x141);
            pv = DPP_ADD(pv, 0x140);
            mysum = (n == li) ? pv : mysum;
        }
        {
            float2 duv = du[cb][n][ch];
            float resv = rs[cb][n][ch];
            float outv = (mysum + duv.y * Dval) * silu_f(resv);
            ysb[((size_t)((b << 10) + l0 + n) << 11) + d0 + ch] = f2bf(outv);
        }
        if (more) {
            du[cb ^ 1][sli][sc] = make_float2(g_d, g_u);
            bc[cb ^ 1][sli][sc] = make_float2(g_b, g_c);
            rs[cb ^ 1][sli][sc] = g_r;
        }
        __syncthreads();
        cb ^= 1;
    }
}

extern "C" void kernel_launch(void* const* d_in, const int* in_sizes, int n_in,
                              void* d_out, int out_size, void* d_ws, size_t ws_size,
                              hipStream_t stream)
{
    const float* x      = (const float*)d_in[0];
    const float* W_in   = (const float*)d_in[1];
    const float* conv_w = (const float*)d_in[2];
    const float* conv_b = (const float*)d_in[3];
    const float* W_x    = (const float*)d_in[4];
    const float* W_dt   = (const float*)d_in[5];
    const float* b_dt   = (const float*)d_in[6];
    const float* A_log  = (const float*)d_in[7];
    const float* Dv     = (const float*)d_in[8];
    const float* W_out  = (const float*)d_in[9];
    float* out = (float*)d_out;

    // fp32 regions
    float* ws       = (float*)d_ws;
    float* xr       = ws;                            // 8,388,608 f  [2048][4096]
    float* u        = xr + (size_t)8388608;          // 4,194,304 f  [2048][2048]
    float* xdbl     = u + (size_t)4194304;           //   262,144 f  [2048][128]
    float* delta    = xdbl + (size_t)262144;         // 4,194,304 f  [2048][2048]
    float* P16      = delta;                         // alias: 16x[2048][128] partials (dead before GEMM4 writes delta)
    float* P2       = xr;                            // alias: 2x[2048][1024] partials (xr dead after scan)
    // bf16 region: 6,460,416 ushorts (12.9 MB)
    unsigned short* bfr = (unsigned short*)(delta + (size_t)4194304);
    unsigned short* xb      = bfr;                      // [0, 2M)       phase 1
    unsigned short* W_inT   = bfr + (size_t)2097152;    // [2M, 6.29M)   phase 1
    unsigned short* ub      = bfr;                      // [0, 4.19M)    phase 2 (after GEMM1)
    unsigned short* W_xTp   = bfr + (size_t)4194304;    // [4.19M, 4.46M) phase 2
    unsigned short* ysb     = bfr;                      // [0, 4.19M)    phase 3 (after gemm3 partials)
    unsigned short* W_outT  = bfr + (size_t)4456448;    // [4.46M, 6.46M)

    // 0. conversions for GEMM1
    to_bf16<<<2048, 256, 0, stream>>>(x, xb, 524288);
    transpose_to_bf16<<<dim3(64, 16), 256, 0, stream>>>(W_in, W_inT, 1024, 4096);
    // 1. xr = x @ W_in   [2048,1024]@[1024,4096]  bf16 MFMA
    gemm_bf16<<<dim3(32, 16, 1), 256, 0, stream>>>(xb, W_inT, xr, 2048, 4096, 1024, 1024);
    // 2. u (+bf16 copy) = silu(causal dwconv(xr[:, :2048]))
    conv_silu<<<16384, 256, 0, stream>>>(xr, conv_w, conv_b, u, ub);
    // 2b. weight transposes (regions freed by GEMM1)
    transpose_wx<<<1024, 256, 0, stream>>>(W_x, W_xTp);
    transpose_to_bf16<<<dim3(16, 32), 256, 0, stream>>>(W_out, W_outT, 2048, 1024);
    // 3. xdbl = u @ W_x  [2048,2048]@[2048,96->128]  split-K=16 bf16 MFMA
    gemm_bf16<<<dim3(1, 16, 16), 256, 0, stream>>>(ub, W_xTp, P16, 2048, 128, 2048, 128);
    reduce16<<<256, 256, 0, stream>>>(P16, xdbl);
    // 4. delta = softplus(xdbl[:, :64] @ W_dt + b_dt)
    gemm_f32<1><<<dim3(32, 32), 256, 0, stream>>>(xdbl, 128, W_dt, 2048, delta, 2048, b_dt, 2048, 64);
    // 5. selective scan + skip + gate -> bf16 (overwrites ub)
    scan_kernel<<<dim3(128, 2), 256, 0, stream>>>(delta, u, xdbl, A_log, xr, Dv, ysb);
    // 6. out = ys @ W_out  [2048,2048]@[2048,1024]  split-K=2 bf16 MFMA (partials over dead xr)
    gemm_bf16<<<dim3(8, 16, 2), 256, 0, stream>>>(ysb, W_outT, P2, 2048, 1024, 2048, 1024);
    reduce2<<<2048, 256, 0, stream>>>(P2, out);
}

// Round 6
// 203.029 us; speedup vs baseline: 3.9836x; 1.0284x over previous
//
#include <hip/hip_runtime.h>
#include <hip/hip_bf16.h>
#include <math.h>

// Mamba block forward. bf16 MFMA GEMMs (split-K for skinny shapes),
// 3-phase segmented selective scan (8 segments) with fused gate.
// Shapes: B=2, L=1024, DIM=1024, DIM_INNER=2048, D_STATE=16, D_CONV=4, DT_RANK=64

#define TILE 64
#define BKK  16
#define LPAD 68

__device__ __forceinline__ float silu_f(float x) {
    return x / (1.f + __expf(-x));
}

__device__ __forceinline__ unsigned short f2bf(float f) {
    __hip_bfloat16 h = __float2bfloat16(f);
    return *(unsigned short*)&h;
}

// ---------------- bf16 MFMA GEMM: C[M,N] = A[M,K] @ BT[N,K]^T ----------------
typedef __attribute__((ext_vector_type(8))) short short8v;
typedef __attribute__((ext_vector_type(4))) float f32x4;

__device__ __forceinline__ void gload16(const void* g, void* lds) {
    __builtin_amdgcn_global_load_lds(
        (const __attribute__((address_space(1))) unsigned int*)g,
        (__attribute__((address_space(3))) unsigned int*)lds, 16, 0, 0);
}

__global__ __launch_bounds__(256) void gemm_bf16(
    const unsigned short* __restrict__ A,   // [M][K]
    const unsigned short* __restrict__ BT,  // [N][K]
    float* __restrict__ C,
    int M, int N, int K, int klen)
{
    __shared__ unsigned short As[128 * 32];
    __shared__ unsigned short Bs[128 * 32];
    const int tid  = threadIdx.x;
    const int wid  = tid >> 6;
    const int lane = tid & 63;
    const int wr = wid >> 1, wc = wid & 1;
    const int row0 = blockIdx.y * 128, col0 = blockIdx.x * 128;
    const int kbeg = blockIdx.z * klen;
    C += (size_t)blockIdx.z * M * N;

    f32x4 acc[4][4] = {};

    const int srow = lane >> 2;
    const int scol = (lane & 3) * 8;

    for (int k0 = kbeg; k0 < kbeg + klen; k0 += 32) {
        #pragma unroll
        for (int c = 0; c < 2; ++c) {
            int chunk = wid * 2 + c;
            gload16(A  + (size_t)(row0 + chunk * 16 + srow) * K + k0 + scol,
                    (void*)(As + chunk * 512));
            gload16(BT + (size_t)(col0 + chunk * 16 + srow) * K + k0 + scol,
                    (void*)(Bs + chunk * 512));
        }
        __syncthreads();
        short8v a[4], b[4];
        #pragma unroll
        for (int i = 0; i < 4; ++i)
            a[i] = *(const short8v*)&As[(wr * 64 + i * 16 + (lane & 15)) * 32 + (lane >> 4) * 8];
        #pragma unroll
        for (int j = 0; j < 4; ++j)
            b[j] = *(const short8v*)&Bs[(wc * 64 + j * 16 + (lane & 15)) * 32 + (lane >> 4) * 8];
        #pragma unroll
        for (int i = 0; i < 4; ++i)
            #pragma unroll
            for (int j = 0; j < 4; ++j)
                acc[i][j] = __builtin_amdgcn_mfma_f32_16x16x32_bf16(a[i], b[j], acc[i][j], 0, 0, 0);
        __syncthreads();
    }

    #pragma unroll
    for (int i = 0; i < 4; ++i) {
        int rbase = row0 + wr * 64 + i * 16 + (lane >> 4) * 4;
        #pragma unroll
        for (int j = 0; j < 4; ++j) {
            int cc = col0 + wc * 64 + j * 16 + (lane & 15);
            #pragma unroll
            for (int r = 0; r < 4; ++r)
                C[(size_t)(rbase + r) * N + cc] = acc[i][j][r];
        }
    }
}

// ---------------- conversions ----------------
__global__ __launch_bounds__(256) void to_bf16(
    const float* __restrict__ src, unsigned short* __restrict__ dst, int n4)
{
    int i = blockIdx.x * 256 + threadIdx.x;
    if (i >= n4) return;
    float4 v = *(const float4*)(src + (size_t)i * 4);
    ushort4 o;
    o.x = f2bf(v.x); o.y = f2bf(v.y); o.z = f2bf(v.z); o.w = f2bf(v.w);
    *(ushort4*)(dst + (size_t)i * 4) = o;
}

__global__ __launch_bounds__(256) void transpose_to_bf16(
    const float* __restrict__ W, unsigned short* __restrict__ WT, int K, int N)
{
    __shared__ float t[64][65];
    const int tx = threadIdx.x & 63, ty = threadIdx.x >> 6;
    const int bk = blockIdx.y * 64, bn = blockIdx.x * 64;
    #pragma unroll
    for (int s = 0; s < 16; ++s)
        t[ty + 4 * s][tx] = W[(size_t)(bk + ty + 4 * s) * N + bn + tx];
    __syncthreads();
    #pragma unroll
    for (int s = 0; s < 16; ++s)
        WT[(size_t)(bn + ty + 4 * s) * K + bk + tx] = f2bf(t[tx][ty + 4 * s]);
}

__global__ __launch_bounds__(256) void transpose_wx(
    const float* __restrict__ Wx, unsigned short* __restrict__ WT)
{
    int idx = blockIdx.x * 256 + threadIdx.x;
    int k = idx & 2047, n = idx >> 11;
    float v = (n < 96) ? Wx[(size_t)k * 96 + n] : 0.f;
    WT[idx] = f2bf(v);
}

__global__ __launch_bounds__(256) void reduce16(
    const float* __restrict__ P, float* __restrict__ dst)
{
    int i = blockIdx.x * 256 + threadIdx.x;
    const float4* P4 = (const float4*)P;
    float4 s = P4[i];
    #pragma unroll
    for (int k = 1; k < 16; ++k) {
        float4 v = P4[i + (size_t)k * 65536];
        s.x += v.x; s.y += v.y; s.z += v.z; s.w += v.w;
    }
    ((float4*)dst)[i] = s;
}

__global__ __launch_bounds__(256) void reduce2(
    const float* __restrict__ P, float* __restrict__ dst)
{
    int i = blockIdx.x * 256 + threadIdx.x;
    const float4* P4 = (const float4*)P;
    float4 a = P4[i], b = P4[i + 524288];
    a.x += b.x; a.y += b.y; a.z += b.z; a.w += b.w;
    ((float4*)dst)[i] = a;
}

// ---------------- fp32 GEMM (GEMM4 only) ----------------
template<int MODE>
__global__ __launch_bounds__(256) void gemm_f32(
    const float* __restrict__ A, int lda,
    const float* __restrict__ B, int ldb,
    float* __restrict__ C, int ldc,
    const float* __restrict__ bias,
    int N, int K)
{
    __shared__ float As[BKK][LPAD];
    __shared__ float Bs[BKK][LPAD];
    const int tid = threadIdx.x;
    const int tx = tid & 15, ty = tid >> 4;
    const int row0 = blockIdx.y * TILE, col0 = blockIdx.x * TILE;

    const int arow = tid >> 2;
    const int acol = (tid & 3) << 2;
    const int brow = tid >> 4;
    const int bcol = (tid & 15) << 2;

    float acc[4][4] = {};

    for (int k0 = 0; k0 < K; k0 += BKK) {
        float4 av = *(const float4*)(A + (size_t)(row0 + arow) * lda + k0 + acol);
        As[acol + 0][arow] = av.x;
        As[acol + 1][arow] = av.y;
        As[acol + 2][arow] = av.z;
        As[acol + 3][arow] = av.w;
        float4 bv = make_float4(0.f, 0.f, 0.f, 0.f);
        if (col0 + bcol < N)
            bv = *(const float4*)(B + (size_t)(k0 + brow) * ldb + col0 + bcol);
        *(float4*)(&Bs[brow][bcol]) = bv;
        __syncthreads();
        #pragma unroll
        for (int k = 0; k < BKK; ++k) {
            float4 a4 = *(const float4*)(&As[k][ty << 2]);
            float4 b4 = *(const float4*)(&Bs[k][tx << 2]);
            float a[4] = {a4.x, a4.y, a4.z, a4.w};
            float bb[4] = {b4.x, b4.y, b4.z, b4.w};
            #pragma unroll
            for (int i = 0; i < 4; ++i)
                #pragma unroll
                for (int j = 0; j < 4; ++j)
                    acc[i][j] = fmaf(a[i], bb[j], acc[i][j]);
        }
        __syncthreads();
    }
    #pragma unroll
    for (int i = 0; i < 4; ++i) {
        int r = row0 + (ty << 2) + i;
        #pragma unroll
        for (int j = 0; j < 4; ++j) {
            int c = col0 + (tx << 2) + j;
            if (c < N) {
                float v = acc[i][j];
                if (MODE == 1) {
                    v += bias[c];
                    v = (v > 20.f) ? v : log1pf(expf(v));
                }
                C[(size_t)r * ldc + c] = v;
            }
        }
    }
}

__global__ __launch_bounds__(256) void conv_silu(
    const float* __restrict__ xr,
    const float* __restrict__ conv_w,
    const float* __restrict__ conv_b,
    float* __restrict__ u,
    unsigned short* __restrict__ ub)
{
    int idx = blockIdx.x * 256 + threadIdx.x;
    int d = idx & 2047;
    int r = idx >> 11;
    int l = r & 1023;
    int b = r >> 10;
    float acc = conv_b[d];
    const float* wp = conv_w + d * 4;
    #pragma unroll
    for (int w = 0; w < 4; ++w) {
        int ls = l + w - 3;
        if (ls >= 0)
            acc = fmaf(xr[((size_t)((b << 10) + ls) << 12) + d], wp[w], acc);
    }
    float uv = silu_f(acc);
    u[idx] = uv;
    ub[idx] = f2bf(uv);
}

// ---------------- segmented selective scan ----------------
// 8 segments of 128 steps. Grid (128 d-groups, 2 batch, 8 seg), 256 threads.
// Segment maps stashed in dead u-half columns of xr (cols 0..2047):
//   Aseg at linear j in [0, 512K), Bseg/h0 at j+512K; stash_idx maps linear ->
//   strided-row layout inside xr.
#define SCAN_T 16
#define NSEG 8
#define SEGLEN 128

__device__ __forceinline__ size_t stash_idx(int j) {
    return ((size_t)(j >> 11) << 12) + (j & 2047);
}

#define DPP_ADD(v, ctrl) ((v) + __int_as_float(__builtin_amdgcn_update_dpp( \
        0, __float_as_int(v), (ctrl), 0xF, 0xF, true)))

// pass1: per-segment affine map (A_seg, B_seg) from h=0. No C/res/y.
__global__ __launch_bounds__(256) void scan_pass1(
    const float* __restrict__ delta,  // [2048][2048]
    const float* __restrict__ u,      // [2048][2048]
    const float* __restrict__ xdbl,   // [2048][128]
    const float* __restrict__ A_log,  // [2048][16]
    float* __restrict__ stash)        // = xr
{
    __shared__ float2 du[2][SCAN_T][17];
    __shared__ float  bs[2][SCAN_T][17];

    const int tid = threadIdx.x;
    const int dg = blockIdx.x, b = blockIdx.y, s = blockIdx.z;
    const int d0 = dg * 16;
    const int ch = tid >> 4, n = tid & 15;
    const float Aval = -__expf(A_log[(d0 + ch) * 16 + n]);
    const int sli = tid >> 4, sc = tid & 15;
    const int lbase = s * SEGLEN;

    float g_d, g_u, g_b;
    {
        size_t row = (size_t)(b << 10) + lbase + sli;
        g_d = delta[(row << 11) + d0 + sc];
        g_u = u[(row << 11) + d0 + sc];
        g_b = xdbl[(row << 7) + 64 + sc];
    }
    du[0][sli][sc] = make_float2(g_d, g_u);
    bs[0][sli][sc] = g_b;
    __syncthreads();

    float h = 0.f, sd = 0.f;
    int cb = 0;
    for (int c = 0; c < SEGLEN / SCAN_T; ++c) {
        const bool more = (c + 1) < SEGLEN / SCAN_T;
        if (more) {
            size_t row = (size_t)(b << 10) + lbase + (c + 1) * SCAN_T + sli;
            g_d = delta[(row << 11) + d0 + sc];
            g_u = u[(row << 11) + d0 + sc];
            g_b = xdbl[(row << 7) + 64 + sc];
        }
        float e_[SCAN_T], f_[SCAN_T];
        #pragma unroll
        for (int li = 0; li < SCAN_T; ++li) {
            float2 duv = du[cb][li][ch];
            float bv = bs[cb][li][n];
            e_[li] = __expf(duv.x * Aval);
            f_[li] = duv.x * bv * duv.y;
            sd += duv.x;
        }
        #pragma unroll
        for (int li = 0; li < SCAN_T; ++li)
            h = fmaf(e_[li], h, f_[li]);
        if (more) {
            du[cb ^ 1][sli][sc] = make_float2(g_d, g_u);
            bs[cb ^ 1][sli][sc] = g_b;
        }
        __syncthreads();
        cb ^= 1;
    }
    int j = (((b << 3) + s) * 128 + dg) * 256 + tid;
    stash[stash_idx(j)] = __expf(Aval * sd);         // A_seg
    stash[stash_idx(j + 524288)] = h;                // B_seg
}

// compose: h0[s] = B_{s-1} + A_{s-1} * h0[s-1]; overwrite Bseg with h0.
__global__ __launch_bounds__(256) void scan_compose(float* __restrict__ stash)
{
    int t = blockIdx.x * 256 + threadIdx.x;   // 65536 = (b, d, n)
    int b = t >> 15, dn = t & 32767;
    float h = 0.f;
    #pragma unroll
    for (int s = 0; s < NSEG; ++s) {
        int j = ((b << 3) + s) * 32768 + dn;
        float A = stash[stash_idx(j)];
        float B = stash[stash_idx(j + 524288)];
        stash[stash_idx(j + 524288)] = h;
        h = fmaf(A, h, B);
    }
}

// pass3: replay segment from h0, compute y + skip + gate -> bf16.
__global__ __launch_bounds__(256) void scan_pass3(
    const float* __restrict__ delta,
    const float* __restrict__ u,
    const float* __restrict__ xdbl,
    const float* __restrict__ A_log,
    const float* __restrict__ xr,     // res = cols 2048..4095; stash in cols 0..2047
    const float* __restrict__ Dv,
    unsigned short* __restrict__ ysb)
{
    __shared__ float2 du[2][SCAN_T][17];
    __shared__ float2 bc[2][SCAN_T][17];
    __shared__ float  rs[2][SCAN_T][17];

    const int tid = threadIdx.x;
    const int dg = blockIdx.x, b = blockIdx.y, s = blockIdx.z;
    const int d0 = dg * 16;
    const int ch = tid >> 4, n = tid & 15;
    const float Aval = -__expf(A_log[(d0 + ch) * 16 + n]);
    const float Dval = Dv[d0 + ch];
    const int sli = tid >> 4, sc = tid & 15;
    const int lbase = s * SEGLEN;

    float h = xr[stash_idx((((b << 3) + s) * 128 + dg) * 256 + tid + 524288)];

    float g_d, g_u, g_b, g_c, g_r;
    {
        size_t row = (size_t)(b << 10) + lbase + sli;
        g_d = delta[(row << 11) + d0 + sc];
        g_u = u[(row << 11) + d0 + sc];
        g_b = xdbl[(row << 7) + 64 + sc];
        g_c = xdbl[(row << 7) + 80 + sc];
        g_r = xr[(row << 12) + 2048 + d0 + sc];
    }
    du[0][sli][sc] = make_float2(g_d, g_u);
    bc[0][sli][sc] = make_float2(g_b, g_c);
    rs[0][sli][sc] = g_r;
    __syncthreads();

    int cb = 0;
    for (int c = 0; c < SEGLEN / SCAN_T; ++c) {
        const int l0 = lbase + c * SCAN_T;
        const bool more = (c + 1) < SEGLEN / SCAN_T;
        if (more) {
            size_t row = (size_t)(b << 10) + l0 + SCAN_T + sli;
            g_d = delta[(row << 11) + d0 + sc];
            g_u = u[(row << 11) + d0 + sc];
            g_b = xdbl[(row << 7) + 64 + sc];
            g_c = xdbl[(row << 7) + 80 + sc];
            g_r = xr[(row << 12) + 2048 + d0 + sc];
        }
        float e_[SCAN_T], f_[SCAN_T], c_[SCAN_T];
        #pragma unroll
        for (int li = 0; li < SCAN_T; ++li) {
            float2 duv = du[cb][li][ch];
            float2 bcv = bc[cb][li][n];
            e_[li] = __expf(duv.x * Aval);
            f_[li] = duv.x * bcv.x * duv.y;
            c_[li] = bcv.y;
        }
        float mysum = 0.f;
        #pragma unroll
        for (int li = 0; li < SCAN_T; ++li) {
            h = fmaf(e_[li], h, f_[li]);
            float pv = h * c_[li];
            pv = DPP_ADD(pv, 0xB1);
            pv = DPP_ADD(pv, 0x4E);
            pv = DPP_ADD(pv, 0x141);
            pv = DPP_ADD(pv, 0x140);
            mysum = (n == li) ? pv : mysum;
        }
        {
            float2 duv = du[cb][n][ch];
            float resv = rs[cb][n][ch];
            float outv = (mysum + duv.y * Dval) * silu_f(resv);
            ysb[((size_t)((b << 10) + l0 + n) << 11) + d0 + ch] = f2bf(outv);
        }
        if (more) {
            du[cb ^ 1][sli][sc] = make_float2(g_d, g_u);
            bc[cb ^ 1][sli][sc] = make_float2(g_b, g_c);
            rs[cb ^ 1][sli][sc] = g_r;
        }
        __syncthreads();
        cb ^= 1;
    }
}

extern "C" void kernel_launch(void* const* d_in, const int* in_sizes, int n_in,
                              void* d_out, int out_size, void* d_ws, size_t ws_size,
                              hipStream_t stream)
{
    const float* x      = (const float*)d_in[0];
    const float* W_in   = (const float*)d_in[1];
    const float* conv_w = (const float*)d_in[2];
    const float* conv_b = (const float*)d_in[3];
    const float* W_x    = (const float*)d_in[4];
    const float* W_dt   = (const float*)d_in[5];
    const float* b_dt   = (const float*)d_in[6];
    const float* A_log  = (const float*)d_in[7];
    const float* Dv     = (const float*)d_in[8];
    const float* W_out  = (const float*)d_in[9];
    float* out = (float*)d_out;

    float* ws       = (float*)d_ws;
    float* xr       = ws;                            // [2048][4096]; u-half cols reused as stash after conv
    float* u        = xr + (size_t)8388608;          // [2048][2048]
    float* xdbl     = u + (size_t)4194304;           // [2048][128]
    float* delta    = xdbl + (size_t)262144;         // [2048][2048]
    float* P16      = delta;                         // alias: split-K partials (dead before GEMM4)
    float* P2       = xr;                            // alias: GEMM7 partials (xr fully dead after pass3)
    unsigned short* bfr = (unsigned short*)(delta + (size_t)4194304);
    unsigned short* xb      = bfr;
    unsigned short* W_inT   = bfr + (size_t)2097152;
    unsigned short* ub      = bfr;
    unsigned short* W_xTp   = bfr + (size_t)4194304;
    unsigned short* ysb     = bfr;
    unsigned short* W_outT  = bfr + (size_t)4456448;

    // 0. conversions for GEMM1
    to_bf16<<<2048, 256, 0, stream>>>(x, xb, 524288);
    transpose_to_bf16<<<dim3(64, 16), 256, 0, stream>>>(W_in, W_inT, 1024, 4096);
    // 1. xr = x @ W_in  (bf16 MFMA)
    gemm_bf16<<<dim3(32, 16, 1), 256, 0, stream>>>(xb, W_inT, xr, 2048, 4096, 1024, 1024);
    // 2. u (+bf16) = silu(causal dwconv(xr[:, :2048]))
    conv_silu<<<16384, 256, 0, stream>>>(xr, conv_w, conv_b, u, ub);
    // 2b. weight transposes
    transpose_wx<<<1024, 256, 0, stream>>>(W_x, W_xTp);
    transpose_to_bf16<<<dim3(16, 32), 256, 0, stream>>>(W_out, W_outT, 2048, 1024);
    // 3. xdbl = u @ W_x  split-K=16 bf16 MFMA
    gemm_bf16<<<dim3(1, 16, 16), 256, 0, stream>>>(ub, W_xTp, P16, 2048, 128, 2048, 128);
    reduce16<<<256, 256, 0, stream>>>(P16, xdbl);
    // 4. delta = softplus(xdbl[:, :64] @ W_dt + b_dt)
    gemm_f32<1><<<dim3(32, 32), 256, 0, stream>>>(xdbl, 128, W_dt, 2048, delta, 2048, b_dt, 2048, 64);
    // 5. segmented scan: per-segment maps -> h0 compose -> replay with gate
    scan_pass1<<<dim3(128, 2, 8), 256, 0, stream>>>(delta, u, xdbl, A_log, xr);
    scan_compose<<<256, 256, 0, stream>>>(xr);
    scan_pass3<<<dim3(128, 2, 8), 256, 0, stream>>>(delta, u, xdbl, A_log, xr, Dv, ysb);
    // 6. out = ys @ W_out  split-K=2 bf16 MFMA
    gemm_bf16<<<dim3(8, 16, 2), 256, 0, stream>>>(ysb, W_outT, P2, 2048, 1024, 2048, 1024);
    reduce2<<<2048, 256, 0, stream>>>(P2, out);
}

// Round 7
// 188.184 us; speedup vs baseline: 4.2979x; 1.0789x over previous
//
#include <hip/hip_runtime.h>
#include <hip/hip_bf16.h>
#include <math.h>

// Mamba block forward. ALL matmuls in bf16 MFMA (split-K for skinny shapes),
// 3-phase segmented selective scan (8 segments) with fused gate.
// Shapes: B=2, L=1024, DIM=1024, DIM_INNER=2048, D_STATE=16, D_CONV=4, DT_RANK=64

__device__ __forceinline__ float silu_f(float x) {
    return x / (1.f + __expf(-x));
}

__device__ __forceinline__ unsigned short f2bf(float f) {
    __hip_bfloat16 h = __float2bfloat16(f);
    return *(unsigned short*)&h;
}

// ---------------- bf16 MFMA GEMM: C[M,N] = A[M,K] @ BT[N,K]^T ----------------
// MODE 0: C = v.  MODE 2: C = softplus(v + bias[col]).
typedef __attribute__((ext_vector_type(8))) short short8v;
typedef __attribute__((ext_vector_type(4))) float f32x4;

__device__ __forceinline__ void gload16(const void* g, void* lds) {
    __builtin_amdgcn_global_load_lds(
        (const __attribute__((address_space(1))) unsigned int*)g,
        (__attribute__((address_space(3))) unsigned int*)lds, 16, 0, 0);
}

template<int MODE>
__global__ __launch_bounds__(256) void gemm_bf16(
    const unsigned short* __restrict__ A,   // [M][K]
    const unsigned short* __restrict__ BT,  // [N][K]
    float* __restrict__ C,
    const float* __restrict__ bias,
    int M, int N, int K, int klen)
{
    __shared__ unsigned short As[128 * 32];
    __shared__ unsigned short Bs[128 * 32];
    const int tid  = threadIdx.x;
    const int wid  = tid >> 6;
    const int lane = tid & 63;
    const int wr = wid >> 1, wc = wid & 1;
    const int row0 = blockIdx.y * 128, col0 = blockIdx.x * 128;
    const int kbeg = blockIdx.z * klen;
    C += (size_t)blockIdx.z * M * N;

    f32x4 acc[4][4] = {};

    const int srow = lane >> 2;
    const int scol = (lane & 3) * 8;

    for (int k0 = kbeg; k0 < kbeg + klen; k0 += 32) {
        #pragma unroll
        for (int c = 0; c < 2; ++c) {
            int chunk = wid * 2 + c;
            gload16(A  + (size_t)(row0 + chunk * 16 + srow) * K + k0 + scol,
                    (void*)(As + chunk * 512));
            gload16(BT + (size_t)(col0 + chunk * 16 + srow) * K + k0 + scol,
                    (void*)(Bs + chunk * 512));
        }
        __syncthreads();
        short8v a[4], b[4];
        #pragma unroll
        for (int i = 0; i < 4; ++i)
            a[i] = *(const short8v*)&As[(wr * 64 + i * 16 + (lane & 15)) * 32 + (lane >> 4) * 8];
        #pragma unroll
        for (int j = 0; j < 4; ++j)
            b[j] = *(const short8v*)&Bs[(wc * 64 + j * 16 + (lane & 15)) * 32 + (lane >> 4) * 8];
        #pragma unroll
        for (int i = 0; i < 4; ++i)
            #pragma unroll
            for (int j = 0; j < 4; ++j)
                acc[i][j] = __builtin_amdgcn_mfma_f32_16x16x32_bf16(a[i], b[j], acc[i][j], 0, 0, 0);
        __syncthreads();
    }

    #pragma unroll
    for (int i = 0; i < 4; ++i) {
        int rbase = row0 + wr * 64 + i * 16 + (lane >> 4) * 4;
        #pragma unroll
        for (int j = 0; j < 4; ++j) {
            int cc = col0 + wc * 64 + j * 16 + (lane & 15);
            float bi = (MODE == 2) ? bias[cc] : 0.f;
            #pragma unroll
            for (int r = 0; r < 4; ++r) {
                float v = acc[i][j][r];
                if (MODE == 2) {
                    v += bi;
                    v = (v > 20.f) ? v : __logf(1.f + __expf(v));
                }
                C[(size_t)(rbase + r) * N + cc] = v;
            }
        }
    }
}

// ---------------- conversions ----------------
__global__ __launch_bounds__(256) void to_bf16(
    const float* __restrict__ src, unsigned short* __restrict__ dst, int n4)
{
    int i = blockIdx.x * 256 + threadIdx.x;
    if (i >= n4) return;
    float4 v = *(const float4*)(src + (size_t)i * 4);
    ushort4 o;
    o.x = f2bf(v.x); o.y = f2bf(v.y); o.z = f2bf(v.z); o.w = f2bf(v.w);
    *(ushort4*)(dst + (size_t)i * 4) = o;
}

__global__ __launch_bounds__(256) void transpose_to_bf16(
    const float* __restrict__ W, unsigned short* __restrict__ WT, int K, int N)
{
    __shared__ float t[64][65];
    const int tx = threadIdx.x & 63, ty = threadIdx.x >> 6;
    const int bk = blockIdx.y * 64, bn = blockIdx.x * 64;
    #pragma unroll
    for (int s = 0; s < 16; ++s)
        t[ty + 4 * s][tx] = W[(size_t)(bk + ty + 4 * s) * N + bn + tx];
    __syncthreads();
    #pragma unroll
    for (int s = 0; s < 16; ++s)
        WT[(size_t)(bn + ty + 4 * s) * K + bk + tx] = f2bf(t[tx][ty + 4 * s]);
}

// W_x[2048][96] fp32 -> WT[128][2048] bf16, rows 96..127 zeroed.
__global__ __launch_bounds__(256) void transpose_wx(
    const float* __restrict__ Wx, unsigned short* __restrict__ WT)
{
    int idx = blockIdx.x * 256 + threadIdx.x;
    int k = idx & 2047, n = idx >> 11;
    float v = (n < 96) ? Wx[(size_t)k * 96 + n] : 0.f;
    WT[idx] = f2bf(v);
}

// W_dt[64][2048] fp32 -> WT[2048][128] bf16, cols 64..127 zeroed.
__global__ __launch_bounds__(256) void transpose_wdt(
    const float* __restrict__ Wdt, unsigned short* __restrict__ WT)
{
    int idx = blockIdx.x * 256 + threadIdx.x;   // over 2048*128
    int k = idx & 127, n = idx >> 7;
    float v = (k < 64) ? Wdt[(size_t)k * 2048 + n] : 0.f;
    WT[idx] = f2bf(v);
}

// xdbl[2048][128] = sum of 16 split-K partials; also emit bf16 copy.
__global__ __launch_bounds__(256) void reduce16(
    const float* __restrict__ P, float* __restrict__ dst,
    unsigned short* __restrict__ dstb)
{
    int i = blockIdx.x * 256 + threadIdx.x;   // float4 index, 65536 total
    const float4* P4 = (const float4*)P;
    float4 s = P4[i];
    #pragma unroll
    for (int k = 1; k < 16; ++k) {
        float4 v = P4[i + (size_t)k * 65536];
        s.x += v.x; s.y += v.y; s.z += v.z; s.w += v.w;
    }
    ((float4*)dst)[i] = s;
    ushort4 o;
    o.x = f2bf(s.x); o.y = f2bf(s.y); o.z = f2bf(s.z); o.w = f2bf(s.w);
    ((ushort4*)dstb)[i] = o;
}

__global__ __launch_bounds__(256) void reduce2(
    const float* __restrict__ P, float* __restrict__ dst)
{
    int i = blockIdx.x * 256 + threadIdx.x;
    const float4* P4 = (const float4*)P;
    float4 a = P4[i], b = P4[i + 524288];
    a.x += b.x; a.y += b.y; a.z += b.z; a.w += b.w;
    ((float4*)dst)[i] = a;
}

__global__ __launch_bounds__(256) void conv_silu(
    const float* __restrict__ xr,
    const float* __restrict__ conv_w,
    const float* __restrict__ conv_b,
    float* __restrict__ u,
    unsigned short* __restrict__ ub)
{
    int idx = blockIdx.x * 256 + threadIdx.x;
    int d = idx & 2047;
    int r = idx >> 11;
    int l = r & 1023;
    int b = r >> 10;
    float acc = conv_b[d];
    const float* wp = conv_w + d * 4;
    #pragma unroll
    for (int w = 0; w < 4; ++w) {
        int ls = l + w - 3;
        if (ls >= 0)
            acc = fmaf(xr[((size_t)((b << 10) + ls) << 12) + d], wp[w], acc);
    }
    float uv = silu_f(acc);
    u[idx] = uv;
    ub[idx] = f2bf(uv);
}

// ---------------- segmented selective scan ----------------
#define SCAN_T 16
#define NSEG 8
#define SEGLEN 128

__device__ __forceinline__ size_t stash_idx(int j) {
    return ((size_t)(j >> 11) << 12) + (j & 2047);
}

#define DPP_ADD(v, ctrl) ((v) + __int_as_float(__builtin_amdgcn_update_dpp( \
        0, __float_as_int(v), (ctrl), 0xF, 0xF, true)))

__global__ __launch_bounds__(256) void scan_pass1(
    const float* __restrict__ delta,
    const float* __restrict__ u,
    const float* __restrict__ xdbl,
    const float* __restrict__ A_log,
    float* __restrict__ stash)
{
    __shared__ float2 du[2][SCAN_T][17];
    __shared__ float  bs[2][SCAN_T][17];

    const int tid = threadIdx.x;
    const int dg = blockIdx.x, b = blockIdx.y, s = blockIdx.z;
    const int d0 = dg * 16;
    const int ch = tid >> 4, n = tid & 15;
    const float Aval = -__expf(A_log[(d0 + ch) * 16 + n]);
    const int sli = tid >> 4, sc = tid & 15;
    const int lbase = s * SEGLEN;

    float g_d, g_u, g_b;
    {
        size_t row = (size_t)(b << 10) + lbase + sli;
        g_d = delta[(row << 11) + d0 + sc];
        g_u = u[(row << 11) + d0 + sc];
        g_b = xdbl[(row << 7) + 64 + sc];
    }
    du[0][sli][sc] = make_float2(g_d, g_u);
    bs[0][sli][sc] = g_b;
    __syncthreads();

    float h = 0.f, sd = 0.f;
    int cb = 0;
    for (int c = 0; c < SEGLEN / SCAN_T; ++c) {
        const bool more = (c + 1) < SEGLEN / SCAN_T;
        if (more) {
            size_t row = (size_t)(b << 10) + lbase + (c + 1) * SCAN_T + sli;
            g_d = delta[(row << 11) + d0 + sc];
            g_u = u[(row << 11) + d0 + sc];
            g_b = xdbl[(row << 7) + 64 + sc];
        }
        float e_[SCAN_T], f_[SCAN_T];
        #pragma unroll
        for (int li = 0; li < SCAN_T; ++li) {
            float2 duv = du[cb][li][ch];
            float bv = bs[cb][li][n];
            e_[li] = __expf(duv.x * Aval);
            f_[li] = duv.x * bv * duv.y;
            sd += duv.x;
        }
        #pragma unroll
        for (int li = 0; li < SCAN_T; ++li)
            h = fmaf(e_[li], h, f_[li]);
        if (more) {
            du[cb ^ 1][sli][sc] = make_float2(g_d, g_u);
            bs[cb ^ 1][sli][sc] = g_b;
        }
        __syncthreads();
        cb ^= 1;
    }
    int j = (((b << 3) + s) * 128 + dg) * 256 + tid;
    stash[stash_idx(j)] = __expf(Aval * sd);         // A_seg
    stash[stash_idx(j + 524288)] = h;                // B_seg
}

__global__ __launch_bounds__(256) void scan_compose(float* __restrict__ stash)
{
    int t = blockIdx.x * 256 + threadIdx.x;
    int b = t >> 15, dn = t & 32767;
    float h = 0.f;
    #pragma unroll
    for (int s = 0; s < NSEG; ++s) {
        int j = ((b << 3) + s) * 32768 + dn;
        float A = stash[stash_idx(j)];
        float B = stash[stash_idx(j + 524288)];
        stash[stash_idx(j + 524288)] = h;
        h = fmaf(A, h, B);
    }
}

__global__ __launch_bounds__(256) void scan_pass3(
    const float* __restrict__ delta,
    const float* __restrict__ u,
    const float* __restrict__ xdbl,
    const float* __restrict__ A_log,
    const float* __restrict__ xr,
    const float* __restrict__ Dv,
    unsigned short* __restrict__ ysb)
{
    __shared__ float2 du[2][SCAN_T][17];
    __shared__ float2 bc[2][SCAN_T][17];
    __shared__ float  rs[2][SCAN_T][17];

    const int tid = threadIdx.x;
    const int dg = blockIdx.x, b = blockIdx.y, s = blockIdx.z;
    const int d0 = dg * 16;
    const int ch = tid >> 4, n = tid & 15;
    const float Aval = -__expf(A_log[(d0 + ch) * 16 + n]);
    const float Dval = Dv[d0 + ch];
    const int sli = tid >> 4, sc = tid & 15;
    const int lbase = s * SEGLEN;

    float h = xr[stash_idx((((b << 3) + s) * 128 + dg) * 256 + tid + 524288)];

    float g_d, g_u, g_b, g_c, g_r;
    {
        size_t row = (size_t)(b << 10) + lbase + sli;
        g_d = delta[(row << 11) + d0 + sc];
        g_u = u[(row << 11) + d0 + sc];
        g_b = xdbl[(row << 7) + 64 + sc];
        g_c = xdbl[(row << 7) + 80 + sc];
        g_r = xr[(row << 12) + 2048 + d0 + sc];
    }
    du[0][sli][sc] = make_float2(g_d, g_u);
    bc[0][sli][sc] = make_float2(g_b, g_c);
    rs[0][sli][sc] = g_r;
    __syncthreads();

    int cb = 0;
    for (int c = 0; c < SEGLEN / SCAN_T; ++c) {
        const int l0 = lbase + c * SCAN_T;
        const bool more = (c + 1) < SEGLEN / SCAN_T;
        if (more) {
            size_t row = (size_t)(b << 10) + l0 + SCAN_T + sli;
            g_d = delta[(row << 11) + d0 + sc];
            g_u = u[(row << 11) + d0 + sc];
            g_b = xdbl[(row << 7) + 64 + sc];
            g_c = xdbl[(row << 7) + 80 + sc];
            g_r = xr[(row << 12) + 2048 + d0 + sc];
        }
        float e_[SCAN_T], f_[SCAN_T], c_[SCAN_T];
        #pragma unroll
        for (int li = 0; li < SCAN_T; ++li) {
            float2 duv = du[cb][li][ch];
            float2 bcv = bc[cb][li][n];
            e_[li] = __expf(duv.x * Aval);
            f_[li] = duv.x * bcv.x * duv.y;
            c_[li] = bcv.y;
        }
        float mysum = 0.f;
        #pragma unroll
        for (int li = 0; li < SCAN_T; ++li) {
            h = fmaf(e_[li], h, f_[li]);
            float pv = h * c_[li];
            pv = DPP_ADD(pv, 0xB1);
            pv = DPP_ADD(pv, 0x4E);
            pv = DPP_ADD(pv, 0x141);
            pv = DPP_ADD(pv, 0x140);
            mysum = (n == li) ? pv : mysum;
        }
        {
            float2 duv = du[cb][n][ch];
            float resv = rs[cb][n][ch];
            float outv = (mysum + duv.y * Dval) * silu_f(resv);
            ysb[((size_t)((b << 10) + l0 + n) << 11) + d0 + ch] = f2bf(outv);
        }
        if (more) {
            du[cb ^ 1][sli][sc] = make_float2(g_d, g_u);
            bc[cb ^ 1][sli][sc] = make_float2(g_b, g_c);
            rs[cb ^ 1][sli][sc] = g_r;
        }
        __syncthreads();
        cb ^= 1;
    }
}

extern "C" void kernel_launch(void* const* d_in, const int* in_sizes, int n_in,
                              void* d_out, int out_size, void* d_ws, size_t ws_size,
                              hipStream_t stream)
{
    const float* x      = (const float*)d_in[0];
    const float* W_in   = (const float*)d_in[1];
    const float* conv_w = (const float*)d_in[2];
    const float* conv_b = (const float*)d_in[3];
    const float* W_x    = (const float*)d_in[4];
    const float* W_dt   = (const float*)d_in[5];
    const float* b_dt   = (const float*)d_in[6];
    const float* A_log  = (const float*)d_in[7];
    const float* Dv     = (const float*)d_in[8];
    const float* W_out  = (const float*)d_in[9];
    float* out = (float*)d_out;

    float* ws       = (float*)d_ws;
    float* xr       = ws;                            // [2048][4096]; u-half reused as scan stash
    float* u        = xr + (size_t)8388608;          // [2048][2048]
    float* xdbl     = u + (size_t)4194304;           // [2048][128]
    float* delta    = xdbl + (size_t)262144;         // [2048][2048]
    float* P16      = delta;                         // alias: split-K partials (dead before delta written)
    float* P2       = xr;                            // alias: GEMM7 partials (xr dead after pass3)
    unsigned short* bfr = (unsigned short*)(delta + (size_t)4194304);
    unsigned short* xb      = bfr;                      // phase 1
    unsigned short* W_inT   = bfr + (size_t)2097152;    // phase 1
    unsigned short* ub      = bfr;                      // phase 2
    unsigned short* W_xTp   = bfr + (size_t)4194304;
    unsigned short* ysb     = bfr;                      // phase 3
    unsigned short* W_outT  = bfr + (size_t)4456448;
    unsigned short* W_dtTp  = bfr + (size_t)6553600;    // [2048][128]
    unsigned short* xdbl_b  = bfr + (size_t)6815744;    // [2048][128]

    // 0. conversions for GEMM1
    to_bf16<<<2048, 256, 0, stream>>>(x, xb, 524288);
    transpose_to_bf16<<<dim3(64, 16), 256, 0, stream>>>(W_in, W_inT, 1024, 4096);
    // 1. xr = x @ W_in  (bf16 MFMA)
    gemm_bf16<0><<<dim3(32, 16, 1), 256, 0, stream>>>(xb, W_inT, xr, nullptr, 2048, 4096, 1024, 1024);
    // 2. u (+bf16) = silu(causal dwconv(xr[:, :2048]))
    conv_silu<<<16384, 256, 0, stream>>>(xr, conv_w, conv_b, u, ub);
    // 2b. weight transposes
    transpose_wx<<<1024, 256, 0, stream>>>(W_x, W_xTp);
    transpose_wdt<<<1024, 256, 0, stream>>>(W_dt, W_dtTp);
    transpose_to_bf16<<<dim3(16, 32), 256, 0, stream>>>(W_out, W_outT, 2048, 1024);
    // 3. xdbl = u @ W_x  split-K=16 bf16 MFMA (+ bf16 copy of xdbl)
    gemm_bf16<0><<<dim3(1, 16, 16), 256, 0, stream>>>(ub, W_xTp, P16, nullptr, 2048, 128, 2048, 128);
    reduce16<<<256, 256, 0, stream>>>(P16, xdbl, xdbl_b);
    // 4. delta = softplus(xdbl @ W_dt + b_dt)  bf16 MFMA, K padded 64->128
    gemm_bf16<2><<<dim3(16, 16, 1), 256, 0, stream>>>(xdbl_b, W_dtTp, delta, b_dt, 2048, 2048, 128, 128);
    // 5. segmented scan
    scan_pass1<<<dim3(128, 2, 8), 256, 0, stream>>>(delta, u, xdbl, A_log, xr);
    scan_compose<<<256, 256, 0, stream>>>(xr);
    scan_pass3<<<dim3(128, 2, 8), 256, 0, stream>>>(delta, u, xdbl, A_log, xr, Dv, ysb);
    // 6. out = ys @ W_out  split-K=2 bf16 MFMA
    gemm_bf16<0><<<dim3(8, 16, 2), 256, 0, stream>>>(ysb, W_outT, P2, nullptr, 2048, 1024, 2048, 1024);
    reduce2<<<2048, 256, 0, stream>>>(P2, out);
}

// Round 8
// 168.382 us; speedup vs baseline: 4.8033x; 1.1176x over previous
//
#include <hip/hip_runtime.h>
#include <hip/hip_bf16.h>
#include <math.h>

// Mamba block forward. All matmuls bf16 MFMA; bf16 delta/u through the scan;
// fused prep kernel; 2-pass segmented scan with inline h0 composition.
// Shapes: B=2, L=1024, DIM=1024, DIM_INNER=2048, D_STATE=16, D_CONV=4, DT_RANK=64

__device__ __forceinline__ float silu_f(float x) {
    return x / (1.f + __expf(-x));
}
__device__ __forceinline__ unsigned short f2bf(float f) {
    __hip_bfloat16 h = __float2bfloat16(f);
    return *(unsigned short*)&h;
}
__device__ __forceinline__ float bf2f(unsigned short u) {
    return __uint_as_float((unsigned)u << 16);
}

// ---------------- bf16 MFMA GEMM: C[M,N] = A[M,K] @ BT[N,K]^T ----------------
// MODE 0: fp32 C = v.   MODE 3: bf16 Cb = softplus(v + bias[col]).
typedef __attribute__((ext_vector_type(8))) short short8v;
typedef __attribute__((ext_vector_type(4))) float f32x4;

__device__ __forceinline__ void gload16(const void* g, void* lds) {
    __builtin_amdgcn_global_load_lds(
        (const __attribute__((address_space(1))) unsigned int*)g,
        (__attribute__((address_space(3))) unsigned int*)lds, 16, 0, 0);
}

template<int MODE>
__global__ __launch_bounds__(256) void gemm_bf16(
    const unsigned short* __restrict__ A,   // [M][K]
    const unsigned short* __restrict__ BT,  // [N][K]
    float* __restrict__ C,
    unsigned short* __restrict__ Cb,
    const float* __restrict__ bias,
    int M, int N, int K, int klen)
{
    __shared__ unsigned short As[128 * 32];
    __shared__ unsigned short Bs[128 * 32];
    const int tid  = threadIdx.x;
    const int wid  = tid >> 6;
    const int lane = tid & 63;
    const int wr = wid >> 1, wc = wid & 1;
    const int row0 = blockIdx.y * 128, col0 = blockIdx.x * 128;
    const int kbeg = blockIdx.z * klen;
    C += (size_t)blockIdx.z * M * N;

    f32x4 acc[4][4] = {};

    const int srow = lane >> 2;
    const int scol = (lane & 3) * 8;

    for (int k0 = kbeg; k0 < kbeg + klen; k0 += 32) {
        #pragma unroll
        for (int c = 0; c < 2; ++c) {
            int chunk = wid * 2 + c;
            gload16(A  + (size_t)(row0 + chunk * 16 + srow) * K + k0 + scol,
                    (void*)(As + chunk * 512));
            gload16(BT + (size_t)(col0 + chunk * 16 + srow) * K + k0 + scol,
                    (void*)(Bs + chunk * 512));
        }
        __syncthreads();
        short8v a[4], b[4];
        #pragma unroll
        for (int i = 0; i < 4; ++i)
            a[i] = *(const short8v*)&As[(wr * 64 + i * 16 + (lane & 15)) * 32 + (lane >> 4) * 8];
        #pragma unroll
        for (int j = 0; j < 4; ++j)
            b[j] = *(const short8v*)&Bs[(wc * 64 + j * 16 + (lane & 15)) * 32 + (lane >> 4) * 8];
        #pragma unroll
        for (int i = 0; i < 4; ++i)
            #pragma unroll
            for (int j = 0; j < 4; ++j)
                acc[i][j] = __builtin_amdgcn_mfma_f32_16x16x32_bf16(a[i], b[j], acc[i][j], 0, 0, 0);
        __syncthreads();
    }

    #pragma unroll
    for (int i = 0; i < 4; ++i) {
        int rbase = row0 + wr * 64 + i * 16 + (lane >> 4) * 4;
        #pragma unroll
        for (int j = 0; j < 4; ++j) {
            int cc = col0 + wc * 64 + j * 16 + (lane & 15);
            float bi = (MODE == 3) ? bias[cc] : 0.f;
            #pragma unroll
            for (int r = 0; r < 4; ++r) {
                float v = acc[i][j][r];
                if (MODE == 3) {
                    v += bi;
                    v = (v > 20.f) ? v : __logf(1.f + __expf(v));
                    Cb[(size_t)(rbase + r) * N + cc] = f2bf(v);
                } else {
                    C[(size_t)(rbase + r) * N + cc] = v;
                }
            }
        }
    }
}

// ---------------- fused prep: all input conversions in one kernel ----------
// blocks [0,1024)      : x -> xb (bf16), 8 elems/thread
// blocks [1024,2048)   : W_in[1024][4096] -> W_inT[4096][1024] bf16
// blocks [2048,2560)   : W_out[2048][1024] -> W_outT[1024][2048] bf16
// blocks [2560,3584)   : W_x[2048][96] -> W_xTp[128][2048] bf16 (pad rows 96+)
// blocks [3584,4608)   : W_dt[64][2048] -> W_dtTp[2048][128] bf16 (pad cols 64+)
__device__ __forceinline__ void trans64(
    const float* __restrict__ W, unsigned short* __restrict__ WT,
    int K, int N, int bk, int bn, int tid, float (*t)[65])
{
    const int tx = tid & 63, ty = tid >> 6;
    #pragma unroll
    for (int s = 0; s < 16; ++s)
        t[ty + 4 * s][tx] = W[(size_t)(bk + ty + 4 * s) * N + bn + tx];
    __syncthreads();
    #pragma unroll
    for (int s = 0; s < 16; ++s)
        WT[(size_t)(bn + ty + 4 * s) * K + bk + tx] = f2bf(t[tx][ty + 4 * s]);
}

__global__ __launch_bounds__(256) void prep_all(
    const float* __restrict__ x,
    const float* __restrict__ W_in,
    const float* __restrict__ W_out,
    const float* __restrict__ Wx,
    const float* __restrict__ Wdt,
    unsigned short* __restrict__ xb,
    unsigned short* __restrict__ W_inT,
    unsigned short* __restrict__ W_outT,
    unsigned short* __restrict__ W_xTp,
    unsigned short* __restrict__ W_dtTp)
{
    __shared__ float t[64][65];
    const int bid = blockIdx.x;
    const int tid = threadIdx.x;
    if (bid < 1024) {
        int i = bid * 256 + tid;             // 262144 threads x 8 elems
        float4 v0 = *(const float4*)(x + (size_t)i * 8);
        float4 v1 = *(const float4*)(x + (size_t)i * 8 + 4);
        ushort4 o0, o1;
        o0.x = f2bf(v0.x); o0.y = f2bf(v0.y); o0.z = f2bf(v0.z); o0.w = f2bf(v0.w);
        o1.x = f2bf(v1.x); o1.y = f2bf(v1.y); o1.z = f2bf(v1.z); o1.w = f2bf(v1.w);
        *(ushort4*)(xb + (size_t)i * 8) = o0;
        *(ushort4*)(xb + (size_t)i * 8 + 4) = o1;
    } else if (bid < 2048) {
        int tt = bid - 1024;                 // W_in: 64 n-tiles x 16 k-tiles
        trans64(W_in, W_inT, 1024, 4096, (tt >> 6) * 64, (tt & 63) * 64, tid, t);
    } else if (bid < 2560) {
        int tt = bid - 2048;                 // W_out: 16 n-tiles x 32 k-tiles
        trans64(W_out, W_outT, 2048, 1024, (tt >> 4) * 64, (tt & 15) * 64, tid, t);
    } else if (bid < 3584) {
        int idx = (bid - 2560) * 256 + tid;  // over 128*2048
        int k = idx & 2047, n = idx >> 11;
        float v = (n < 96) ? Wx[(size_t)k * 96 + n] : 0.f;
        W_xTp[idx] = f2bf(v);
    } else {
        int idx = (bid - 3584) * 256 + tid;  // over 2048*128
        int k = idx & 127, n = idx >> 7;
        float v = (k < 64) ? Wdt[(size_t)k * 2048 + n] : 0.f;
        W_dtTp[idx] = f2bf(v);
    }
}

// xdbl[2048][128] = sum of 16 split-K partials; fp32 + bf16 copies.
__global__ __launch_bounds__(256) void reduce16(
    const float* __restrict__ P, float* __restrict__ dst,
    unsigned short* __restrict__ dstb)
{
    int i = blockIdx.x * 256 + threadIdx.x;
    const float4* P4 = (const float4*)P;
    float4 s = P4[i];
    #pragma unroll
    for (int k = 1; k < 16; ++k) {
        float4 v = P4[i + (size_t)k * 65536];
        s.x += v.x; s.y += v.y; s.z += v.z; s.w += v.w;
    }
    ((float4*)dst)[i] = s;
    ushort4 o;
    o.x = f2bf(s.x); o.y = f2bf(s.y); o.z = f2bf(s.z); o.w = f2bf(s.w);
    ((ushort4*)dstb)[i] = o;
}

__global__ __launch_bounds__(256) void reduce2(
    const float* __restrict__ P, float* __restrict__ dst)
{
    int i = blockIdx.x * 256 + threadIdx.x;
    const float4* P4 = (const float4*)P;
    float4 a = P4[i], b = P4[i + 524288];
    a.x += b.x; a.y += b.y; a.z += b.z; a.w += b.w;
    ((float4*)dst)[i] = a;
}

// u(bf16 only) = silu(causal depthwise conv(xr[:, :2048]) + conv_b)
__global__ __launch_bounds__(256) void conv_silu(
    const float* __restrict__ xr,
    const float* __restrict__ conv_w,
    const float* __restrict__ conv_b,
    unsigned short* __restrict__ ub)
{
    int idx = blockIdx.x * 256 + threadIdx.x;
    int d = idx & 2047;
    int r = idx >> 11;
    int l = r & 1023;
    int b = r >> 10;
    float acc = conv_b[d];
    const float* wp = conv_w + d * 4;
    #pragma unroll
    for (int w = 0; w < 4; ++w) {
        int ls = l + w - 3;
        if (ls >= 0)
            acc = fmaf(xr[((size_t)((b << 10) + ls) << 12) + d], wp[w], acc);
    }
    ub[idx] = f2bf(silu_f(acc));
}

// ---------------- segmented selective scan (bf16 delta/u inputs) ----------
#define SCAN_T 16
#define NSEG 8
#define SEGLEN 128

__device__ __forceinline__ size_t stash_idx(int j) {
    return ((size_t)(j >> 11) << 12) + (j & 2047);
}

#define DPP_ADD(v, ctrl) ((v) + __int_as_float(__builtin_amdgcn_update_dpp( \
        0, __float_as_int(v), (ctrl), 0xF, 0xF, true)))

__global__ __launch_bounds__(256) void scan_pass1(
    const unsigned short* __restrict__ delta_b,  // [2048][2048] bf16
    const unsigned short* __restrict__ ub,       // [2048][2048] bf16
    const float* __restrict__ xdbl,              // [2048][128] fp32
    const float* __restrict__ A_log,
    float* __restrict__ stash)                   // = xr cols 0..2047
{
    __shared__ float2 du[2][SCAN_T][17];
    __shared__ float  bs[2][SCAN_T][17];

    const int tid = threadIdx.x;
    const int dg = blockIdx.x, b = blockIdx.y, s = blockIdx.z;
    const int d0 = dg * 16;
    const int ch = tid >> 4, n = tid & 15;
    const float Aval = -__expf(A_log[(d0 + ch) * 16 + n]);
    const int sli = tid >> 4, sc = tid & 15;
    const int lbase = s * SEGLEN;

    float g_d, g_u, g_b;
    {
        size_t row = (size_t)(b << 10) + lbase + sli;
        g_d = bf2f(delta_b[(row << 11) + d0 + sc]);
        g_u = bf2f(ub[(row << 11) + d0 + sc]);
        g_b = xdbl[(row << 7) + 64 + sc];
    }
    du[0][sli][sc] = make_float2(g_d, g_u);
    bs[0][sli][sc] = g_b;
    __syncthreads();

    float h = 0.f, sd = 0.f;
    int cb = 0;
    for (int c = 0; c < SEGLEN / SCAN_T; ++c) {
        const bool more = (c + 1) < SEGLEN / SCAN_T;
        if (more) {
            size_t row = (size_t)(b << 10) + lbase + (c + 1) * SCAN_T + sli;
            g_d = bf2f(delta_b[(row << 11) + d0 + sc]);
            g_u = bf2f(ub[(row << 11) + d0 + sc]);
            g_b = xdbl[(row << 7) + 64 + sc];
        }
        float e_[SCAN_T], f_[SCAN_T];
        #pragma unroll
        for (int li = 0; li < SCAN_T; ++li) {
            float2 duv = du[cb][li][ch];
            float bv = bs[cb][li][n];
            e_[li] = __expf(duv.x * Aval);
            f_[li] = duv.x * bv * duv.y;
            sd += duv.x;
        }
        #pragma unroll
        for (int li = 0; li < SCAN_T; ++li)
            h = fmaf(e_[li], h, f_[li]);
        if (more) {
            du[cb ^ 1][sli][sc] = make_float2(g_d, g_u);
            bs[cb ^ 1][sli][sc] = g_b;
        }
        __syncthreads();
        cb ^= 1;
    }
    int j = (((b << 3) + s) * 128 + dg) * 256 + tid;
    stash[stash_idx(j)] = __expf(Aval * sd);         // A_seg
    stash[stash_idx(j + 524288)] = h;                // B_seg
}

__global__ __launch_bounds__(256) void scan_pass3(
    const unsigned short* __restrict__ delta_b,
    const unsigned short* __restrict__ ub,
    const float* __restrict__ xdbl,
    const float* __restrict__ A_log,
    const float* __restrict__ xr,   // stash in cols 0..2047; res = cols 2048..4095
    const float* __restrict__ Dv,
    unsigned short* __restrict__ ysb)
{
    __shared__ float2 du[2][SCAN_T][17];
    __shared__ float2 bc[2][SCAN_T][17];
    __shared__ float  rs[2][SCAN_T][17];

    const int tid = threadIdx.x;
    const int dg = blockIdx.x, b = blockIdx.y, s = blockIdx.z;
    const int d0 = dg * 16;
    const int ch = tid >> 4, n = tid & 15;
    const float Aval = -__expf(A_log[(d0 + ch) * 16 + n]);
    const float Dval = Dv[d0 + ch];
    const int sli = tid >> 4, sc = tid & 15;
    const int lbase = s * SEGLEN;

    // inline h0 composition from per-segment (A_seg, B_seg) maps
    float h = 0.f;
    for (int sp = 0; sp < s; ++sp) {
        int j = (((b << 3) + sp) * 128 + dg) * 256 + tid;
        h = fmaf(xr[stash_idx(j)], h, xr[stash_idx(j + 524288)]);
    }

    float g_d, g_u, g_b, g_c, g_r;
    {
        size_t row = (size_t)(b << 10) + lbase + sli;
        g_d = bf2f(delta_b[(row << 11) + d0 + sc]);
        g_u = bf2f(ub[(row << 11) + d0 + sc]);
        g_b = xdbl[(row << 7) + 64 + sc];
        g_c = xdbl[(row << 7) + 80 + sc];
        g_r = xr[(row << 12) + 2048 + d0 + sc];
    }
    du[0][sli][sc] = make_float2(g_d, g_u);
    bc[0][sli][sc] = make_float2(g_b, g_c);
    rs[0][sli][sc] = g_r;
    __syncthreads();

    int cb = 0;
    for (int c = 0; c < SEGLEN / SCAN_T; ++c) {
        const int l0 = lbase + c * SCAN_T;
        const bool more = (c + 1) < SEGLEN / SCAN_T;
        if (more) {
            size_t row = (size_t)(b << 10) + l0 + SCAN_T + sli;
            g_d = bf2f(delta_b[(row << 11) + d0 + sc]);
            g_u = bf2f(ub[(row << 11) + d0 + sc]);
            g_b = xdbl[(row << 7) + 64 + sc];
            g_c = xdbl[(row << 7) + 80 + sc];
            g_r = xr[(row << 12) + 2048 + d0 + sc];
        }
        float e_[SCAN_T], f_[SCAN_T], c_[SCAN_T];
        #pragma unroll
        for (int li = 0; li < SCAN_T; ++li) {
            float2 duv = du[cb][li][ch];
            float2 bcv = bc[cb][li][n];
            e_[li] = __expf(duv.x * Aval);
            f_[li] = duv.x * bcv.x * duv.y;
            c_[li] = bcv.y;
        }
        float mysum = 0.f;
        #pragma unroll
        for (int li = 0; li < SCAN_T; ++li) {
            h = fmaf(e_[li], h, f_[li]);
            float pv = h * c_[li];
            pv = DPP_ADD(pv, 0xB1);
            pv = DPP_ADD(pv, 0x4E);
            pv = DPP_ADD(pv, 0x141);
            pv = DPP_ADD(pv, 0x140);
            mysum = (n == li) ? pv : mysum;
        }
        {
            float2 duv = du[cb][n][ch];
            float resv = rs[cb][n][ch];
            float outv = (mysum + duv.y * Dval) * silu_f(resv);
            ysb[((size_t)((b << 10) + l0 + n) << 11) + d0 + ch] = f2bf(outv);
        }
        if (more) {
            du[cb ^ 1][sli][sc] = make_float2(g_d, g_u);
            bc[cb ^ 1][sli][sc] = make_float2(g_b, g_c);
            rs[cb ^ 1][sli][sc] = g_r;
        }
        __syncthreads();
        cb ^= 1;
    }
}

extern "C" void kernel_launch(void* const* d_in, const int* in_sizes, int n_in,
                              void* d_out, int out_size, void* d_ws, size_t ws_size,
                              hipStream_t stream)
{
    const float* x      = (const float*)d_in[0];
    const float* W_in   = (const float*)d_in[1];
    const float* conv_w = (const float*)d_in[2];
    const float* conv_b = (const float*)d_in[3];
    const float* W_x    = (const float*)d_in[4];
    const float* W_dt   = (const float*)d_in[5];
    const float* b_dt   = (const float*)d_in[6];
    const float* A_log  = (const float*)d_in[7];
    const float* Dv     = (const float*)d_in[8];
    const float* W_out  = (const float*)d_in[9];
    float* out = (float*)d_out;

    // fp32 regions (floats from base) — ws is ~268 MB, we use ~112 MB, no tight aliasing
    float* ws    = (float*)d_ws;
    float* xr    = ws;                               // [2048][4096]; cols 0..2047 reused as scan stash
    float* xdbl  = ws + (size_t)8388608;             // [2048][128]
    float* P16   = ws + (size_t)8650752;             // 16 x [2048][128]
    float* P2    = ws + (size_t)12845056;            // 2 x [2048][1024]
    unsigned short* bfr = (unsigned short*)(ws + (size_t)17039360);
    unsigned short* xb      = bfr;                       // [2048][1024]
    unsigned short* W_inT   = bfr + (size_t)2097152;     // [4096][1024]
    unsigned short* W_xTp   = bfr + (size_t)6291456;     // [128][2048]
    unsigned short* W_dtTp  = bfr + (size_t)6553600;     // [2048][128]
    unsigned short* W_outT  = bfr + (size_t)6815744;     // [1024][2048]
    unsigned short* ub      = bfr + (size_t)8912896;     // [2048][2048]
    unsigned short* delta_b = bfr + (size_t)13107200;    // [2048][2048]
    unsigned short* ysb     = bfr + (size_t)17301504;    // [2048][2048]
    unsigned short* xdbl_b  = bfr + (size_t)21495808;    // [2048][128]

    // 1. all input conversions fused
    prep_all<<<4608, 256, 0, stream>>>(x, W_in, W_out, W_x, W_dt,
                                       xb, W_inT, W_outT, W_xTp, W_dtTp);
    // 2. xr = x @ W_in  (bf16 MFMA)
    gemm_bf16<0><<<dim3(32, 16, 1), 256, 0, stream>>>(xb, W_inT, xr, nullptr, nullptr, 2048, 4096, 1024, 1024);
    // 3. u(bf16) = silu(causal dwconv(xr[:, :2048]))
    conv_silu<<<16384, 256, 0, stream>>>(xr, conv_w, conv_b, ub);
    // 4. xdbl = u @ W_x  split-K=16 bf16 MFMA -> fp32+bf16 xdbl
    gemm_bf16<0><<<dim3(1, 16, 16), 256, 0, stream>>>(ub, W_xTp, P16, nullptr, nullptr, 2048, 128, 2048, 128);
    reduce16<<<256, 256, 0, stream>>>(P16, xdbl, xdbl_b);
    // 5. delta(bf16) = softplus(xdbl @ W_dt + b_dt)  bf16 MFMA, K padded to 128
    gemm_bf16<3><<<dim3(16, 16, 1), 256, 0, stream>>>(xdbl_b, W_dtTp, nullptr, delta_b, b_dt, 2048, 2048, 128, 128);
    // 6. segmented scan: per-segment maps -> replay (h0 composed inline)
    scan_pass1<<<dim3(128, 2, 8), 256, 0, stream>>>(delta_b, ub, xdbl, A_log, xr);
    scan_pass3<<<dim3(128, 2, 8), 256, 0, stream>>>(delta_b, ub, xdbl, A_log, xr, Dv, ysb);
    // 7. out = ys @ W_out  split-K=2 bf16 MFMA
    gemm_bf16<0><<<dim3(8, 16, 2), 256, 0, stream>>>(ysb, W_outT, P2, nullptr, nullptr, 2048, 1024, 2048, 1024);
    reduce2<<<2048, 256, 0, stream>>>(P2, out);
}

// Round 9
// 155.702 us; speedup vs baseline: 5.1945x; 1.0814x over previous
//
#include <hip/hip_runtime.h>
#include <hip/hip_bf16.h>
#include <math.h>

// Mamba block forward. All matmuls bf16 MFMA; bf16 activations end-to-end;
// weight transposes folded into GEMM1 dispatch; segmented scan (8 seg).
// Shapes: B=2, L=1024, DIM=1024, DIM_INNER=2048, D_STATE=16, D_CONV=4, DT_RANK=64

__device__ __forceinline__ float silu_f(float x) {
    return x / (1.f + __expf(-x));
}
__device__ __forceinline__ unsigned short f2bf(float f) {
    __hip_bfloat16 h = __float2bfloat16(f);
    return *(unsigned short*)&h;
}
__device__ __forceinline__ float bf2f(unsigned short u) {
    return __uint_as_float((unsigned)u << 16);
}

typedef __attribute__((ext_vector_type(8))) short short8v;
typedef __attribute__((ext_vector_type(4))) float f32x4;

__device__ __forceinline__ void gload16(const void* g, void* lds) {
    __builtin_amdgcn_global_load_lds(
        (const __attribute__((address_space(1))) unsigned int*)g,
        (__attribute__((address_space(3))) unsigned int*)lds, 16, 0, 0);
}

// ---------------- bf16 MFMA GEMM core: C[M,N] = A[M,K] @ BT[N,K]^T ----------
// MODE 0: fp32 C.  MODE 3: bf16 Cb = softplus(v + bias[col]), paired stores.
// MODE 4: bf16 Cb = v, paired stores.
template<int MODE>
__device__ __forceinline__ void gemm_core(
    const unsigned short* __restrict__ A,
    const unsigned short* __restrict__ BT,
    float* __restrict__ C, unsigned short* __restrict__ Cb,
    const float* __restrict__ bias,
    int M, int N, int K, int kbeg, int klen,
    int bx, int by, unsigned short* As, unsigned short* Bs)
{
    const int tid  = threadIdx.x;
    const int wid  = tid >> 6;
    const int lane = tid & 63;
    const int wr = wid >> 1, wc = wid & 1;
    const int row0 = by * 128, col0 = bx * 128;

    f32x4 acc[4][4] = {};

    const int srow = lane >> 2;
    const int scol = (lane & 3) * 8;

    for (int k0 = kbeg; k0 < kbeg + klen; k0 += 32) {
        #pragma unroll
        for (int c = 0; c < 2; ++c) {
            int chunk = wid * 2 + c;
            gload16(A  + (size_t)(row0 + chunk * 16 + srow) * K + k0 + scol,
                    (void*)(As + chunk * 512));
            gload16(BT + (size_t)(col0 + chunk * 16 + srow) * K + k0 + scol,
                    (void*)(Bs + chunk * 512));
        }
        __syncthreads();
        short8v a[4], b[4];
        #pragma unroll
        for (int i = 0; i < 4; ++i)
            a[i] = *(const short8v*)&As[(wr * 64 + i * 16 + (lane & 15)) * 32 + (lane >> 4) * 8];
        #pragma unroll
        for (int j = 0; j < 4; ++j)
            b[j] = *(const short8v*)&Bs[(wc * 64 + j * 16 + (lane & 15)) * 32 + (lane >> 4) * 8];
        #pragma unroll
        for (int i = 0; i < 4; ++i)
            #pragma unroll
            for (int j = 0; j < 4; ++j)
                acc[i][j] = __builtin_amdgcn_mfma_f32_16x16x32_bf16(a[i], b[j], acc[i][j], 0, 0, 0);
        __syncthreads();
    }

    #pragma unroll
    for (int i = 0; i < 4; ++i) {
        int rbase = row0 + wr * 64 + i * 16 + (lane >> 4) * 4;
        #pragma unroll
        for (int j = 0; j < 4; ++j) {
            int cc = col0 + wc * 64 + j * 16 + (lane & 15);
            float bi = (MODE == 3) ? bias[cc] : 0.f;
            #pragma unroll
            for (int r = 0; r < 4; ++r) {
                float v = acc[i][j][r];
                if (MODE == 0) {
                    C[(size_t)(rbase + r) * N + cc] = v;
                } else {
                    if (MODE == 3) {
                        v += bi;
                        v = (v > 20.f) ? v : __logf(1.f + __expf(v));
                    }
                    unsigned short m = f2bf(v);
                    unsigned other = (unsigned)__shfl_xor((int)m, 1, 64) & 0xffffu;
                    if (!(lane & 1))
                        *(unsigned*)(Cb + (size_t)(rbase + r) * N + cc) =
                            (unsigned)m | (other << 16);
                }
            }
        }
    }
}

// Standalone GEMM with blockIdx.z K-split (partials at C + z*M*N).
template<int MODE>
__global__ __launch_bounds__(256) void gemm_bf16(
    const unsigned short* __restrict__ A,
    const unsigned short* __restrict__ BT,
    float* __restrict__ C,
    unsigned short* __restrict__ Cb,
    const float* __restrict__ bias,
    int M, int N, int K, int klen)
{
    __shared__ unsigned short As[128 * 32];
    __shared__ unsigned short Bs[128 * 32];
    gemm_core<MODE>(A, BT, C + (size_t)blockIdx.z * M * N, Cb, bias,
                    M, N, K, blockIdx.z * klen, klen,
                    blockIdx.x, blockIdx.y, As, Bs);
}

// 64x64 fp32->bf16 transpose tile helper
__device__ __forceinline__ void trans64(
    const float* __restrict__ W, unsigned short* __restrict__ WT,
    int K, int N, int bk, int bn, int tid, float (*t)[65])
{
    const int tx = tid & 63, ty = tid >> 6;
    #pragma unroll
    for (int s = 0; s < 16; ++s)
        t[ty + 4 * s][tx] = W[(size_t)(bk + ty + 4 * s) * N + bn + tx];
    __syncthreads();
    #pragma unroll
    for (int s = 0; s < 16; ++s)
        WT[(size_t)(bn + ty + 4 * s) * K + bk + tx] = f2bf(t[tx][ty + 4 * s]);
}

// ---------------- GEMM1 + independent weight transposes in one dispatch -----
// blocks [0,512)     : xr_b = x @ W_in (bf16 out, paired stores)
// blocks [512,1024)  : W_out[2048][1024] -> W_outT[1024][2048]
// blocks [1024,1280) : W_x[2048][96] -> W_xTp[128][2048] (pad rows 96+)
// blocks [1280,1536) : W_dt[64][2048] -> W_dtTp[2048][128] (pad cols 64+)
__global__ __launch_bounds__(256) void gemm1_fused(
    const unsigned short* __restrict__ xb,
    const unsigned short* __restrict__ W_inT,
    unsigned short* __restrict__ xrb,
    const float* __restrict__ W_out,
    const float* __restrict__ Wx,
    const float* __restrict__ Wdt,
    unsigned short* __restrict__ W_outT,
    unsigned short* __restrict__ W_xTp,
    unsigned short* __restrict__ W_dtTp)
{
    __shared__ char smem[64 * 65 * 4];   // 16.6 KB, union of both uses
    const int bid = blockIdx.x;
    const int tid = threadIdx.x;
    if (bid < 512) {
        unsigned short* As = (unsigned short*)smem;
        unsigned short* Bs = As + 128 * 32;
        gemm_core<4>(xb, W_inT, nullptr, xrb, nullptr,
                     2048, 4096, 1024, 0, 1024, bid & 31, bid >> 5, As, Bs);
    } else if (bid < 1024) {
        int tt = bid - 512;                  // 32 k-tiles x 16 n-tiles
        trans64(W_out, W_outT, 2048, 1024, (tt >> 4) * 64, (tt & 15) * 64,
                tid, (float(*)[65])smem);
    } else if (bid < 1280) {
        int idx4 = (bid - 1024) * 256 + tid; // W_xTp [128][2048], 4 k/thread
        int n = idx4 >> 9, k0 = (idx4 & 511) << 2;
        ushort4 o;
        o.x = f2bf((n < 96) ? Wx[(size_t)(k0 + 0) * 96 + n] : 0.f);
        o.y = f2bf((n < 96) ? Wx[(size_t)(k0 + 1) * 96 + n] : 0.f);
        o.z = f2bf((n < 96) ? Wx[(size_t)(k0 + 2) * 96 + n] : 0.f);
        o.w = f2bf((n < 96) ? Wx[(size_t)(k0 + 3) * 96 + n] : 0.f);
        *(ushort4*)(W_xTp + (size_t)idx4 * 4) = o;
    } else {
        int idx4 = (bid - 1280) * 256 + tid; // W_dtTp [2048][128], 4 k/thread
        int n = idx4 >> 5, k0 = (idx4 & 31) << 2;
        ushort4 o;
        o.x = f2bf((k0 + 0 < 64) ? Wdt[(size_t)(k0 + 0) * 2048 + n] : 0.f);
        o.y = f2bf((k0 + 1 < 64) ? Wdt[(size_t)(k0 + 1) * 2048 + n] : 0.f);
        o.z = f2bf((k0 + 2 < 64) ? Wdt[(size_t)(k0 + 2) * 2048 + n] : 0.f);
        o.w = f2bf((k0 + 3 < 64) ? Wdt[(size_t)(k0 + 3) * 2048 + n] : 0.f);
        *(ushort4*)(W_dtTp + (size_t)idx4 * 4) = o;
    }
}

// ---------------- prep: x -> bf16, W_in -> W_inT (needed before GEMM1) ------
__global__ __launch_bounds__(256) void prep(
    const float* __restrict__ x,
    const float* __restrict__ W_in,
    unsigned short* __restrict__ xb,
    unsigned short* __restrict__ W_inT)
{
    __shared__ float t[64][65];
    const int bid = blockIdx.x;
    const int tid = threadIdx.x;
    if (bid < 1024) {
        int i = bid * 256 + tid;             // 8 elems/thread
        float4 v0 = *(const float4*)(x + (size_t)i * 8);
        float4 v1 = *(const float4*)(x + (size_t)i * 8 + 4);
        ushort4 o0, o1;
        o0.x = f2bf(v0.x); o0.y = f2bf(v0.y); o0.z = f2bf(v0.z); o0.w = f2bf(v0.w);
        o1.x = f2bf(v1.x); o1.y = f2bf(v1.y); o1.z = f2bf(v1.z); o1.w = f2bf(v1.w);
        *(ushort4*)(xb + (size_t)i * 8) = o0;
        *(ushort4*)(xb + (size_t)i * 8 + 4) = o1;
    } else {
        int tt = bid - 1024;                 // W_in: 16 k-tiles x 64 n-tiles
        trans64(W_in, W_inT, 1024, 4096, (tt >> 6) * 64, (tt & 63) * 64, tid, t);
    }
}

// xdbl[2048][128] = sum of 16 split-K partials; fp32 + bf16 copies.
__global__ __launch_bounds__(256) void reduce16(
    const float* __restrict__ P, float* __restrict__ dst,
    unsigned short* __restrict__ dstb)
{
    int i = blockIdx.x * 256 + threadIdx.x;
    const float4* P4 = (const float4*)P;
    float4 s = P4[i];
    #pragma unroll
    for (int k = 1; k < 16; ++k) {
        float4 v = P4[i + (size_t)k * 65536];
        s.x += v.x; s.y += v.y; s.z += v.z; s.w += v.w;
    }
    ((float4*)dst)[i] = s;
    ushort4 o;
    o.x = f2bf(s.x); o.y = f2bf(s.y); o.z = f2bf(s.z); o.w = f2bf(s.w);
    ((ushort4*)dstb)[i] = o;
}

// out[2048][1024] = sum of 4 split-K partials
__global__ __launch_bounds__(256) void reduce4(
    const float* __restrict__ P, float* __restrict__ dst)
{
    int i = blockIdx.x * 256 + threadIdx.x;   // float4 index, 524288 total
    const float4* P4 = (const float4*)P;
    float4 s = P4[i];
    #pragma unroll
    for (int k = 1; k < 4; ++k) {
        float4 v = P4[i + (size_t)k * 524288];
        s.x += v.x; s.y += v.y; s.z += v.z; s.w += v.w;
    }
    ((float4*)dst)[i] = s;
}

// u(bf16) = silu(causal depthwise conv(xr_b[:, :2048]) + conv_b), 4 ch/thread
__global__ __launch_bounds__(256) void conv_silu(
    const unsigned short* __restrict__ xrb,   // [2048][4096] bf16
    const float* __restrict__ conv_w,
    const float* __restrict__ conv_b,
    unsigned short* __restrict__ ub)          // [2048][2048] bf16
{
    int t = blockIdx.x * 256 + threadIdx.x;   // 1,048,576 threads
    int d4 = (t & 511) << 2;
    int r = t >> 9;
    int l = r & 1023, b = r >> 10;
    float4 cb4 = *(const float4*)(conv_b + d4);
    float acc[4] = {cb4.x, cb4.y, cb4.z, cb4.w};
    float4 cw0 = *(const float4*)(conv_w + (size_t)(d4 + 0) * 4);
    float4 cw1 = *(const float4*)(conv_w + (size_t)(d4 + 1) * 4);
    float4 cw2 = *(const float4*)(conv_w + (size_t)(d4 + 2) * 4);
    float4 cw3 = *(const float4*)(conv_w + (size_t)(d4 + 3) * 4);
    float w0a[4] = {cw0.x, cw0.y, cw0.z, cw0.w};
    float w1a[4] = {cw1.x, cw1.y, cw1.z, cw1.w};
    float w2a[4] = {cw2.x, cw2.y, cw2.z, cw2.w};
    float w3a[4] = {cw3.x, cw3.y, cw3.z, cw3.w};
    #pragma unroll
    for (int w = 0; w < 4; ++w) {
        int ls = l + w - 3;
        if (ls >= 0) {
            ushort4 xv = *(const ushort4*)(xrb + (((size_t)((b << 10) + ls)) << 12) + d4);
            acc[0] = fmaf(bf2f(xv.x), w0a[w], acc[0]);
            acc[1] = fmaf(bf2f(xv.y), w1a[w], acc[1]);
            acc[2] = fmaf(bf2f(xv.z), w2a[w], acc[2]);
            acc[3] = fmaf(bf2f(xv.w), w3a[w], acc[3]);
        }
    }
    ushort4 o;
    o.x = f2bf(silu_f(acc[0]));
    o.y = f2bf(silu_f(acc[1]));
    o.z = f2bf(silu_f(acc[2]));
    o.w = f2bf(silu_f(acc[3]));
    *(ushort4*)(ub + (size_t)t * 4) = o;
}

// ---------------- segmented selective scan (bf16 inputs) -------------------
#define SCAN_T 16
#define NSEG 8
#define SEGLEN 128

#define DPP_ADD(v, ctrl) ((v) + __int_as_float(__builtin_amdgcn_update_dpp( \
        0, __float_as_int(v), (ctrl), 0xF, 0xF, true)))

__global__ __launch_bounds__(256) void scan_pass1(
    const unsigned short* __restrict__ delta_b,
    const unsigned short* __restrict__ ub,
    const float* __restrict__ xdbl,
    const float* __restrict__ A_log,
    float* __restrict__ stash)      // [2][524288]: A_seg, B_seg
{
    __shared__ float2 du[2][SCAN_T][17];
    __shared__ float  bs[2][SCAN_T][17];

    const int tid = threadIdx.x;
    const int dg = blockIdx.x, b = blockIdx.y, s = blockIdx.z;
    const int d0 = dg * 16;
    const int ch = tid >> 4, n = tid & 15;
    const float Aval = -__expf(A_log[(d0 + ch) * 16 + n]);
    const int sli = tid >> 4, sc = tid & 15;
    const int lbase = s * SEGLEN;

    float g_d, g_u, g_b;
    {
        size_t row = (size_t)(b << 10) + lbase + sli;
        g_d = bf2f(delta_b[(row << 11) + d0 + sc]);
        g_u = bf2f(ub[(row << 11) + d0 + sc]);
        g_b = xdbl[(row << 7) + 64 + sc];
    }
    du[0][sli][sc] = make_float2(g_d, g_u);
    bs[0][sli][sc] = g_b;
    __syncthreads();

    float h = 0.f, sd = 0.f;
    int cb = 0;
    for (int c = 0; c < SEGLEN / SCAN_T; ++c) {
        const bool more = (c + 1) < SEGLEN / SCAN_T;
        if (more) {
            size_t row = (size_t)(b << 10) + lbase + (c + 1) * SCAN_T + sli;
            g_d = bf2f(delta_b[(row << 11) + d0 + sc]);
            g_u = bf2f(ub[(row << 11) + d0 + sc]);
            g_b = xdbl[(row << 7) + 64 + sc];
        }
        float e_[SCAN_T], f_[SCAN_T];
        #pragma unroll
        for (int li = 0; li < SCAN_T; ++li) {
            float2 duv = du[cb][li][ch];
            float bv = bs[cb][li][n];
            e_[li] = __expf(duv.x * Aval);
            f_[li] = duv.x * bv * duv.y;
            sd += duv.x;
        }
        #pragma unroll
        for (int li = 0; li < SCAN_T; ++li)
            h = fmaf(e_[li], h, f_[li]);
        if (more) {
            du[cb ^ 1][sli][sc] = make_float2(g_d, g_u);
            bs[cb ^ 1][sli][sc] = g_b;
        }
        __syncthreads();
        cb ^= 1;
    }
    int j = (((b << 3) + s) * 128 + dg) * 256 + tid;
    stash[j] = __expf(Aval * sd);          // A_seg
    stash[j + 524288] = h;                 // B_seg
}

__global__ __launch_bounds__(256) void scan_pass3(
    const unsigned short* __restrict__ delta_b,
    const unsigned short* __restrict__ ub,
    const float* __restrict__ xdbl,
    const float* __restrict__ A_log,
    const unsigned short* __restrict__ xrb,  // res = cols 2048..4095 (bf16)
    const float* __restrict__ stash,
    const float* __restrict__ Dv,
    unsigned short* __restrict__ ysb)
{
    __shared__ float2 du[2][SCAN_T][17];
    __shared__ float2 bc[2][SCAN_T][17];
    __shared__ float  rs[2][SCAN_T][17];

    const int tid = threadIdx.x;
    const int dg = blockIdx.x, b = blockIdx.y, s = blockIdx.z;
    const int d0 = dg * 16;
    const int ch = tid >> 4, n = tid & 15;
    const float Aval = -__expf(A_log[(d0 + ch) * 16 + n]);
    const float Dval = Dv[d0 + ch];
    const int sli = tid >> 4, sc = tid & 15;
    const int lbase = s * SEGLEN;

    // inline h0 composition from per-segment (A_seg, B_seg)
    float h = 0.f;
    for (int sp = 0; sp < s; ++sp) {
        int j = (((b << 3) + sp) * 128 + dg) * 256 + tid;
        h = fmaf(stash[j], h, stash[j + 524288]);
    }

    float g_d, g_u, g_b, g_c, g_r;
    {
        size_t row = (size_t)(b << 10) + lbase + sli;
        g_d = bf2f(delta_b[(row << 11) + d0 + sc]);
        g_u = bf2f(ub[(row << 11) + d0 + sc]);
        g_b = xdbl[(row << 7) + 64 + sc];
        g_c = xdbl[(row << 7) + 80 + sc];
        g_r = bf2f(xrb[(row << 12) + 2048 + d0 + sc]);
    }
    du[0][sli][sc] = make_float2(g_d, g_u);
    bc[0][sli][sc] = make_float2(g_b, g_c);
    rs[0][sli][sc] = g_r;
    __syncthreads();

    int cb = 0;
    for (int c = 0; c < SEGLEN / SCAN_T; ++c) {
        const int l0 = lbase + c * SCAN_T;
        const bool more = (c + 1) < SEGLEN / SCAN_T;
        if (more) {
            size_t row = (size_t)(b << 10) + l0 + SCAN_T + sli;
            g_d = bf2f(delta_b[(row << 11) + d0 + sc]);
            g_u = bf2f(ub[(row << 11) + d0 + sc]);
            g_b = xdbl[(row << 7) + 64 + sc];
            g_c = xdbl[(row << 7) + 80 + sc];
            g_r = bf2f(xrb[(row << 12) + 2048 + d0 + sc]);
        }
        float e_[SCAN_T], f_[SCAN_T], c_[SCAN_T];
        #pragma unroll
        for (int li = 0; li < SCAN_T; ++li) {
            float2 duv = du[cb][li][ch];
            float2 bcv = bc[cb][li][n];
            e_[li] = __expf(duv.x * Aval);
            f_[li] = duv.x * bcv.x * duv.y;
            c_[li] = bcv.y;
        }
        float mysum = 0.f;
        #pragma unroll
        for (int li = 0; li < SCAN_T; ++li) {
            h = fmaf(e_[li], h, f_[li]);
            float pv = h * c_[li];
            pv = DPP_ADD(pv, 0xB1);
            pv = DPP_ADD(pv, 0x4E);
            pv = DPP_ADD(pv, 0x141);
            pv = DPP_ADD(pv, 0x140);
            mysum = (n == li) ? pv : mysum;
        }
        {
            float2 duv = du[cb][n][ch];
            float resv = rs[cb][n][ch];
            float outv = (mysum + duv.y * Dval) * silu_f(resv);
            ysb[((size_t)((b << 10) + l0 + n) << 11) + d0 + ch] = f2bf(outv);
        }
        if (more) {
            du[cb ^ 1][sli][sc] = make_float2(g_d, g_u);
            bc[cb ^ 1][sli][sc] = make_float2(g_b, g_c);
            rs[cb ^ 1][sli][sc] = g_r;
        }
        __syncthreads();
        cb ^= 1;
    }
}

extern "C" void kernel_launch(void* const* d_in, const int* in_sizes, int n_in,
                              void* d_out, int out_size, void* d_ws, size_t ws_size,
                              hipStream_t stream)
{
    const float* x      = (const float*)d_in[0];
    const float* W_in   = (const float*)d_in[1];
    const float* conv_w = (const float*)d_in[2];
    const float* conv_b = (const float*)d_in[3];
    const float* W_x    = (const float*)d_in[4];
    const float* W_dt   = (const float*)d_in[5];
    const float* b_dt   = (const float*)d_in[6];
    const float* A_log  = (const float*)d_in[7];
    const float* Dv     = (const float*)d_in[8];
    const float* W_out  = (const float*)d_in[9];
    float* out = (float*)d_out;

    // fp32 regions
    float* ws    = (float*)d_ws;
    float* xdbl  = ws;                               //   262,144 f [2048][128]
    float* P16   = ws + (size_t)262144;              // 4,194,304 f (16 partials)
    float* P4    = ws + (size_t)4456448;             // 8,388,608 f (4 partials)
    float* stash = ws + (size_t)12845056;            // 1,048,576 f (A_seg,B_seg)
    // bf16 region
    unsigned short* bfr = (unsigned short*)(ws + (size_t)13893632);
    unsigned short* xb      = bfr;                       // [2048][1024]
    unsigned short* W_inT   = bfr + (size_t)2097152;     // [4096][1024]
    unsigned short* W_xTp   = bfr + (size_t)6291456;     // [128][2048]
    unsigned short* W_dtTp  = bfr + (size_t)6553600;     // [2048][128]
    unsigned short* W_outT  = bfr + (size_t)6815744;     // [1024][2048]
    unsigned short* xrb     = bfr + (size_t)8912896;     // [2048][4096]
    unsigned short* ub      = bfr + (size_t)17301504;    // [2048][2048]
    unsigned short* delta_b = bfr + (size_t)21495808;    // [2048][2048]
    unsigned short* ysb     = bfr + (size_t)25690112;    // [2048][2048]
    unsigned short* xdbl_b  = bfr + (size_t)29884416;    // [2048][128]

    // 1. x -> bf16, W_in -> W_inT
    prep<<<2048, 256, 0, stream>>>(x, W_in, xb, W_inT);
    // 2. GEMM1 (bf16 out) + W_out/W_x/W_dt transposes in one dispatch
    gemm1_fused<<<1536, 256, 0, stream>>>(xb, W_inT, xrb, W_out, W_x, W_dt,
                                          W_outT, W_xTp, W_dtTp);
    // 3. u(bf16) = silu(causal dwconv(xr[:, :2048]))
    conv_silu<<<4096, 256, 0, stream>>>(xrb, conv_w, conv_b, ub);
    // 4. xdbl = u @ W_x  split-K=16 bf16 MFMA -> fp32+bf16
    gemm_bf16<0><<<dim3(1, 16, 16), 256, 0, stream>>>(ub, W_xTp, P16, nullptr, nullptr, 2048, 128, 2048, 128);
    reduce16<<<256, 256, 0, stream>>>(P16, xdbl, xdbl_b);
    // 5. delta(bf16) = softplus(xdbl @ W_dt + b_dt), K padded to 128
    gemm_bf16<3><<<dim3(16, 16, 1), 256, 0, stream>>>(xdbl_b, W_dtTp, nullptr, delta_b, b_dt, 2048, 2048, 128, 128);
    // 6. segmented scan: per-segment maps -> replay (h0 composed inline)
    scan_pass1<<<dim3(128, 2, 8), 256, 0, stream>>>(delta_b, ub, xdbl, A_log, stash);
    scan_pass3<<<dim3(128, 2, 8), 256, 0, stream>>>(delta_b, ub, xdbl, A_log, xrb, stash, Dv, ysb);
    // 7. out = ys @ W_out  split-K=4 bf16 MFMA
    gemm_bf16<0><<<dim3(8, 16, 4), 256, 0, stream>>>(ysb, W_outT, P4, nullptr, nullptr, 2048, 1024, 2048, 512);
    reduce4<<<2048, 256, 0, stream>>>(P4, out);
}

// Round 10
// 151.446 us; speedup vs baseline: 5.3404x; 1.0281x over previous
//
#include <hip/hip_runtime.h>
#include <hip/hip_bf16.h>
#include <math.h>

// Mamba block forward. All matmuls bf16 MFMA; bf16 activations end-to-end;
// 64x64-tile MFMA variant for the skinny K=128 GEMMs (4 blocks/CU);
// weight transposes folded into GEMM1 dispatch; segmented scan (8 seg).
// Shapes: B=2, L=1024, DIM=1024, DIM_INNER=2048, D_STATE=16, D_CONV=4, DT_RANK=64

__device__ __forceinline__ float silu_f(float x) {
    return x / (1.f + __expf(-x));
}
__device__ __forceinline__ unsigned short f2bf(float f) {
    __hip_bfloat16 h = __float2bfloat16(f);
    return *(unsigned short*)&h;
}
__device__ __forceinline__ float bf2f(unsigned short u) {
    return __uint_as_float((unsigned)u << 16);
}

typedef __attribute__((ext_vector_type(8))) short short8v;
typedef __attribute__((ext_vector_type(4))) float f32x4;

__device__ __forceinline__ void gload16(const void* g, void* lds) {
    __builtin_amdgcn_global_load_lds(
        (const __attribute__((address_space(1))) unsigned int*)g,
        (__attribute__((address_space(3))) unsigned int*)lds, 16, 0, 0);
}

// ---------------- 128x128 bf16 MFMA GEMM core ------------------------------
// MODE 0: fp32 C.  MODE 4: bf16 Cb = v, paired stores.
template<int MODE>
__device__ __forceinline__ void gemm_core(
    const unsigned short* __restrict__ A,
    const unsigned short* __restrict__ BT,
    float* __restrict__ C, unsigned short* __restrict__ Cb,
    int M, int N, int K, int kbeg, int klen,
    int bx, int by, unsigned short* As, unsigned short* Bs)
{
    const int tid  = threadIdx.x;
    const int wid  = tid >> 6;
    const int lane = tid & 63;
    const int wr = wid >> 1, wc = wid & 1;
    const int row0 = by * 128, col0 = bx * 128;

    f32x4 acc[4][4] = {};

    const int srow = lane >> 2;
    const int scol = (lane & 3) * 8;

    for (int k0 = kbeg; k0 < kbeg + klen; k0 += 32) {
        #pragma unroll
        for (int c = 0; c < 2; ++c) {
            int chunk = wid * 2 + c;
            gload16(A  + (size_t)(row0 + chunk * 16 + srow) * K + k0 + scol,
                    (void*)(As + chunk * 512));
            gload16(BT + (size_t)(col0 + chunk * 16 + srow) * K + k0 + scol,
                    (void*)(Bs + chunk * 512));
        }
        __syncthreads();
        short8v a[4], b[4];
        #pragma unroll
        for (int i = 0; i < 4; ++i)
            a[i] = *(const short8v*)&As[(wr * 64 + i * 16 + (lane & 15)) * 32 + (lane >> 4) * 8];
        #pragma unroll
        for (int j = 0; j < 4; ++j)
            b[j] = *(const short8v*)&Bs[(wc * 64 + j * 16 + (lane & 15)) * 32 + (lane >> 4) * 8];
        #pragma unroll
        for (int i = 0; i < 4; ++i)
            #pragma unroll
            for (int j = 0; j < 4; ++j)
                acc[i][j] = __builtin_amdgcn_mfma_f32_16x16x32_bf16(a[i], b[j], acc[i][j], 0, 0, 0);
        __syncthreads();
    }

    #pragma unroll
    for (int i = 0; i < 4; ++i) {
        int rbase = row0 + wr * 64 + i * 16 + (lane >> 4) * 4;
        #pragma unroll
        for (int j = 0; j < 4; ++j) {
            int cc = col0 + wc * 64 + j * 16 + (lane & 15);
            #pragma unroll
            for (int r = 0; r < 4; ++r) {
                float v = acc[i][j][r];
                if (MODE == 0) {
                    C[(size_t)(rbase + r) * N + cc] = v;
                } else {
                    unsigned short m = f2bf(v);
                    unsigned other = (unsigned)__shfl_xor((int)m, 1, 64) & 0xffffu;
                    if (!(lane & 1))
                        *(unsigned*)(Cb + (size_t)(rbase + r) * N + cc) =
                            (unsigned)m | (other << 16);
                }
            }
        }
    }
}

// Standalone 128x128 GEMM with blockIdx.z K-split (partials at C + z*M*N).
template<int MODE>
__global__ __launch_bounds__(256) void gemm_bf16(
    const unsigned short* __restrict__ A,
    const unsigned short* __restrict__ BT,
    float* __restrict__ C,
    unsigned short* __restrict__ Cb,
    int M, int N, int K, int klen)
{
    __shared__ unsigned short As[128 * 32];
    __shared__ unsigned short Bs[128 * 32];
    gemm_core<MODE>(A, BT, C + (size_t)blockIdx.z * M * N, Cb,
                    M, N, K, blockIdx.z * klen, klen,
                    blockIdx.x, blockIdx.y, As, Bs);
}

// ---------------- 64x64-tile bf16 MFMA GEMM (for skinny K=128 GEMMs) -------
// 4 waves, each owns 32x32 (2x2 frags). MODE 0: fp32 C (split-K partials).
// MODE 3: bf16 Cb = softplus(v + bias[col]), paired stores.
template<int MODE>
__global__ __launch_bounds__(256) void gemm64_bf16(
    const unsigned short* __restrict__ A,
    const unsigned short* __restrict__ BT,
    float* __restrict__ C,
    unsigned short* __restrict__ Cb,
    const float* __restrict__ bias,
    int M, int N, int K, int klen)
{
    __shared__ unsigned short As[64 * 32];
    __shared__ unsigned short Bs[64 * 32];
    const int tid  = threadIdx.x;
    const int wid  = tid >> 6;
    const int lane = tid & 63;
    const int wr = wid >> 1, wc = wid & 1;
    const int row0 = blockIdx.y * 64, col0 = blockIdx.x * 64;
    const int kbeg = blockIdx.z * klen;
    C += (size_t)blockIdx.z * M * N;

    f32x4 acc[2][2] = {};
    const int srow = lane >> 2;
    const int scol = (lane & 3) * 8;

    for (int k0 = kbeg; k0 < kbeg + klen; k0 += 32) {
        gload16(A  + (size_t)(row0 + wid * 16 + srow) * K + k0 + scol,
                (void*)(As + wid * 512));
        gload16(BT + (size_t)(col0 + wid * 16 + srow) * K + k0 + scol,
                (void*)(Bs + wid * 512));
        __syncthreads();
        short8v a[2], b[2];
        #pragma unroll
        for (int i = 0; i < 2; ++i)
            a[i] = *(const short8v*)&As[(wr * 32 + i * 16 + (lane & 15)) * 32 + (lane >> 4) * 8];
        #pragma unroll
        for (int j = 0; j < 2; ++j)
            b[j] = *(const short8v*)&Bs[(wc * 32 + j * 16 + (lane & 15)) * 32 + (lane >> 4) * 8];
        #pragma unroll
        for (int i = 0; i < 2; ++i)
            #pragma unroll
            for (int j = 0; j < 2; ++j)
                acc[i][j] = __builtin_amdgcn_mfma_f32_16x16x32_bf16(a[i], b[j], acc[i][j], 0, 0, 0);
        __syncthreads();
    }

    #pragma unroll
    for (int i = 0; i < 2; ++i) {
        int rbase = row0 + wr * 32 + i * 16 + (lane >> 4) * 4;
        #pragma unroll
        for (int j = 0; j < 2; ++j) {
            int cc = col0 + wc * 32 + j * 16 + (lane & 15);
            float bi = (MODE == 3) ? bias[cc] : 0.f;
            #pragma unroll
            for (int r = 0; r < 4; ++r) {
                float v = acc[i][j][r];
                if (MODE == 0) {
                    C[(size_t)(rbase + r) * N + cc] = v;
                } else {
                    v += bi;
                    v = (v > 20.f) ? v : __logf(1.f + __expf(v));
                    unsigned short m = f2bf(v);
                    unsigned other = (unsigned)__shfl_xor((int)m, 1, 64) & 0xffffu;
                    if (!(lane & 1))
                        *(unsigned*)(Cb + (size_t)(rbase + r) * N + cc) =
                            (unsigned)m | (other << 16);
                }
            }
        }
    }
}

// 64x64 fp32->bf16 transpose tile helper
__device__ __forceinline__ void trans64(
    const float* __restrict__ W, unsigned short* __restrict__ WT,
    int K, int N, int bk, int bn, int tid, float (*t)[65])
{
    const int tx = tid & 63, ty = tid >> 6;
    #pragma unroll
    for (int s = 0; s < 16; ++s)
        t[ty + 4 * s][tx] = W[(size_t)(bk + ty + 4 * s) * N + bn + tx];
    __syncthreads();
    #pragma unroll
    for (int s = 0; s < 16; ++s)
        WT[(size_t)(bn + ty + 4 * s) * K + bk + tx] = f2bf(t[tx][ty + 4 * s]);
}

// ---------------- GEMM1 + independent weight transposes in one dispatch -----
__global__ __launch_bounds__(256) void gemm1_fused(
    const unsigned short* __restrict__ xb,
    const unsigned short* __restrict__ W_inT,
    unsigned short* __restrict__ xrb,
    const float* __restrict__ W_out,
    const float* __restrict__ Wx,
    const float* __restrict__ Wdt,
    unsigned short* __restrict__ W_outT,
    unsigned short* __restrict__ W_xTp,
    unsigned short* __restrict__ W_dtTp)
{
    __shared__ char smem[64 * 65 * 4];
    const int bid = blockIdx.x;
    const int tid = threadIdx.x;
    if (bid < 512) {
        unsigned short* As = (unsigned short*)smem;
        unsigned short* Bs = As + 128 * 32;
        gemm_core<4>(xb, W_inT, nullptr, xrb,
                     2048, 4096, 1024, 0, 1024, bid & 31, bid >> 5, As, Bs);
    } else if (bid < 1024) {
        int tt = bid - 512;
        trans64(W_out, W_outT, 2048, 1024, (tt >> 4) * 64, (tt & 15) * 64,
                tid, (float(*)[65])smem);
    } else if (bid < 1280) {
        int idx4 = (bid - 1024) * 256 + tid;
        int n = idx4 >> 9, k0 = (idx4 & 511) << 2;
        ushort4 o;
        o.x = f2bf((n < 96) ? Wx[(size_t)(k0 + 0) * 96 + n] : 0.f);
        o.y = f2bf((n < 96) ? Wx[(size_t)(k0 + 1) * 96 + n] : 0.f);
        o.z = f2bf((n < 96) ? Wx[(size_t)(k0 + 2) * 96 + n] : 0.f);
        o.w = f2bf((n < 96) ? Wx[(size_t)(k0 + 3) * 96 + n] : 0.f);
        *(ushort4*)(W_xTp + (size_t)idx4 * 4) = o;
    } else {
        int idx4 = (bid - 1280) * 256 + tid;
        int n = idx4 >> 5, k0 = (idx4 & 31) << 2;
        ushort4 o;
        o.x = f2bf((k0 + 0 < 64) ? Wdt[(size_t)(k0 + 0) * 2048 + n] : 0.f);
        o.y = f2bf((k0 + 1 < 64) ? Wdt[(size_t)(k0 + 1) * 2048 + n] : 0.f);
        o.z = f2bf((k0 + 2 < 64) ? Wdt[(size_t)(k0 + 2) * 2048 + n] : 0.f);
        o.w = f2bf((k0 + 3 < 64) ? Wdt[(size_t)(k0 + 3) * 2048 + n] : 0.f);
        *(ushort4*)(W_dtTp + (size_t)idx4 * 4) = o;
    }
}

// ---------------- prep: x -> bf16, W_in -> W_inT ----------------------------
__global__ __launch_bounds__(256) void prep(
    const float* __restrict__ x,
    const float* __restrict__ W_in,
    unsigned short* __restrict__ xb,
    unsigned short* __restrict__ W_inT)
{
    __shared__ float t[64][65];
    const int bid = blockIdx.x;
    const int tid = threadIdx.x;
    if (bid < 1024) {
        int i = bid * 256 + tid;
        float4 v0 = *(const float4*)(x + (size_t)i * 8);
        float4 v1 = *(const float4*)(x + (size_t)i * 8 + 4);
        ushort4 o0, o1;
        o0.x = f2bf(v0.x); o0.y = f2bf(v0.y); o0.z = f2bf(v0.z); o0.w = f2bf(v0.w);
        o1.x = f2bf(v1.x); o1.y = f2bf(v1.y); o1.z = f2bf(v1.z); o1.w = f2bf(v1.w);
        *(ushort4*)(xb + (size_t)i * 8) = o0;
        *(ushort4*)(xb + (size_t)i * 8 + 4) = o1;
    } else {
        int tt = bid - 1024;
        trans64(W_in, W_inT, 1024, 4096, (tt >> 6) * 64, (tt & 63) * 64, tid, t);
    }
}

// xdbl[2048][128] = sum of 16 split-K partials; fp32 + bf16 copies.
__global__ __launch_bounds__(256) void reduce16(
    const float* __restrict__ P, float* __restrict__ dst,
    unsigned short* __restrict__ dstb)
{
    int i = blockIdx.x * 256 + threadIdx.x;
    const float4* P4 = (const float4*)P;
    float4 s = P4[i];
    #pragma unroll
    for (int k = 1; k < 16; ++k) {
        float4 v = P4[i + (size_t)k * 65536];
        s.x += v.x; s.y += v.y; s.z += v.z; s.w += v.w;
    }
    ((float4*)dst)[i] = s;
    ushort4 o;
    o.x = f2bf(s.x); o.y = f2bf(s.y); o.z = f2bf(s.z); o.w = f2bf(s.w);
    ((ushort4*)dstb)[i] = o;
}

// out[2048][1024] = sum of 4 split-K partials
__global__ __launch_bounds__(256) void reduce4(
    const float* __restrict__ P, float* __restrict__ dst)
{
    int i = blockIdx.x * 256 + threadIdx.x;
    const float4* P4 = (const float4*)P;
    float4 s = P4[i];
    #pragma unroll
    for (int k = 1; k < 4; ++k) {
        float4 v = P4[i + (size_t)k * 524288];
        s.x += v.x; s.y += v.y; s.z += v.z; s.w += v.w;
    }
    ((float4*)dst)[i] = s;
}

// u(bf16) = silu(causal depthwise conv(xr_b[:, :2048]) + conv_b), 4 ch/thread
__global__ __launch_bounds__(256) void conv_silu(
    const unsigned short* __restrict__ xrb,
    const float* __restrict__ conv_w,
    const float* __restrict__ conv_b,
    unsigned short* __restrict__ ub)
{
    int t = blockIdx.x * 256 + threadIdx.x;
    int d4 = (t & 511) << 2;
    int r = t >> 9;
    int l = r & 1023, b = r >> 10;
    float4 cb4 = *(const float4*)(conv_b + d4);
    float acc[4] = {cb4.x, cb4.y, cb4.z, cb4.w};
    float4 cw0 = *(const float4*)(conv_w + (size_t)(d4 + 0) * 4);
    float4 cw1 = *(const float4*)(conv_w + (size_t)(d4 + 1) * 4);
    float4 cw2 = *(const float4*)(conv_w + (size_t)(d4 + 2) * 4);
    float4 cw3 = *(const float4*)(conv_w + (size_t)(d4 + 3) * 4);
    float w0a[4] = {cw0.x, cw0.y, cw0.z, cw0.w};
    float w1a[4] = {cw1.x, cw1.y, cw1.z, cw1.w};
    float w2a[4] = {cw2.x, cw2.y, cw2.z, cw2.w};
    float w3a[4] = {cw3.x, cw3.y, cw3.z, cw3.w};
    #pragma unroll
    for (int w = 0; w < 4; ++w) {
        int ls = l + w - 3;
        if (ls >= 0) {
            ushort4 xv = *(const ushort4*)(xrb + (((size_t)((b << 10) + ls)) << 12) + d4);
            acc[0] = fmaf(bf2f(xv.x), w0a[w], acc[0]);
            acc[1] = fmaf(bf2f(xv.y), w1a[w], acc[1]);
            acc[2] = fmaf(bf2f(xv.z), w2a[w], acc[2]);
            acc[3] = fmaf(bf2f(xv.w), w3a[w], acc[3]);
        }
    }
    ushort4 o;
    o.x = f2bf(silu_f(acc[0]));
    o.y = f2bf(silu_f(acc[1]));
    o.z = f2bf(silu_f(acc[2]));
    o.w = f2bf(silu_f(acc[3]));
    *(ushort4*)(ub + (size_t)t * 4) = o;
}

// ---------------- segmented selective scan (bf16 inputs) -------------------
#define SCAN_T 16
#define NSEG 8
#define SEGLEN 128

#define DPP_ADD(v, ctrl) ((v) + __int_as_float(__builtin_amdgcn_update_dpp( \
        0, __float_as_int(v), (ctrl), 0xF, 0xF, true)))

__global__ __launch_bounds__(256) void scan_pass1(
    const unsigned short* __restrict__ delta_b,
    const unsigned short* __restrict__ ub,
    const float* __restrict__ xdbl,
    const float* __restrict__ A_log,
    float* __restrict__ stash)
{
    __shared__ float2 du[2][SCAN_T][17];
    __shared__ float  bs[2][SCAN_T][17];

    const int tid = threadIdx.x;
    const int dg = blockIdx.x, b = blockIdx.y, s = blockIdx.z;
    const int d0 = dg * 16;
    const int ch = tid >> 4, n = tid & 15;
    const float Aval = -__expf(A_log[(d0 + ch) * 16 + n]);
    const int sli = tid >> 4, sc = tid & 15;
    const int lbase = s * SEGLEN;

    float g_d, g_u, g_b;
    {
        size_t row = (size_t)(b << 10) + lbase + sli;
        g_d = bf2f(delta_b[(row << 11) + d0 + sc]);
        g_u = bf2f(ub[(row << 11) + d0 + sc]);
        g_b = xdbl[(row << 7) + 64 + sc];
    }
    du[0][sli][sc] = make_float2(g_d, g_u);
    bs[0][sli][sc] = g_b;
    __syncthreads();

    float h = 0.f, sd = 0.f;
    int cb = 0;
    for (int c = 0; c < SEGLEN / SCAN_T; ++c) {
        const bool more = (c + 1) < SEGLEN / SCAN_T;
        if (more) {
            size_t row = (size_t)(b << 10) + lbase + (c + 1) * SCAN_T + sli;
            g_d = bf2f(delta_b[(row << 11) + d0 + sc]);
            g_u = bf2f(ub[(row << 11) + d0 + sc]);
            g_b = xdbl[(row << 7) + 64 + sc];
        }
        float e_[SCAN_T], f_[SCAN_T];
        #pragma unroll
        for (int li = 0; li < SCAN_T; ++li) {
            float2 duv = du[cb][li][ch];
            float bv = bs[cb][li][n];
            e_[li] = __expf(duv.x * Aval);
            f_[li] = duv.x * bv * duv.y;
            sd += duv.x;
        }
        #pragma unroll
        for (int li = 0; li < SCAN_T; ++li)
            h = fmaf(e_[li], h, f_[li]);
        if (more) {
            du[cb ^ 1][sli][sc] = make_float2(g_d, g_u);
            bs[cb ^ 1][sli][sc] = g_b;
        }
        __syncthreads();
        cb ^= 1;
    }
    int j = (((b << 3) + s) * 128 + dg) * 256 + tid;
    stash[j] = __expf(Aval * sd);
    stash[j + 524288] = h;
}

__global__ __launch_bounds__(256) void scan_pass3(
    const unsigned short* __restrict__ delta_b,
    const unsigned short* __restrict__ ub,
    const float* __restrict__ xdbl,
    const float* __restrict__ A_log,
    const unsigned short* __restrict__ xrb,
    const float* __restrict__ stash,
    const float* __restrict__ Dv,
    unsigned short* __restrict__ ysb)
{
    __shared__ float2 du[2][SCAN_T][17];
    __shared__ float2 bc[2][SCAN_T][17];
    __shared__ float  rs[2][SCAN_T][17];

    const int tid = threadIdx.x;
    const int dg = blockIdx.x, b = blockIdx.y, s = blockIdx.z;
    const int d0 = dg * 16;
    const int ch = tid >> 4, n = tid & 15;
    const float Aval = -__expf(A_log[(d0 + ch) * 16 + n]);
    const float Dval = Dv[d0 + ch];
    const int sli = tid >> 4, sc = tid & 15;
    const int lbase = s * SEGLEN;

    float h = 0.f;
    for (int sp = 0; sp < s; ++sp) {
        int j = (((b << 3) + sp) * 128 + dg) * 256 + tid;
        h = fmaf(stash[j], h, stash[j + 524288]);
    }

    float g_d, g_u, g_b, g_c, g_r;
    {
        size_t row = (size_t)(b << 10) + lbase + sli;
        g_d = bf2f(delta_b[(row << 11) + d0 + sc]);
        g_u = bf2f(ub[(row << 11) + d0 + sc]);
        g_b = xdbl[(row << 7) + 64 + sc];
        g_c = xdbl[(row << 7) + 80 + sc];
        g_r = bf2f(xrb[(row << 12) + 2048 + d0 + sc]);
    }
    du[0][sli][sc] = make_float2(g_d, g_u);
    bc[0][sli][sc] = make_float2(g_b, g_c);
    rs[0][sli][sc] = g_r;
    __syncthreads();

    int cb = 0;
    for (int c = 0; c < SEGLEN / SCAN_T; ++c) {
        const int l0 = lbase + c * SCAN_T;
        const bool more = (c + 1) < SEGLEN / SCAN_T;
        if (more) {
            size_t row = (size_t)(b << 10) + l0 + SCAN_T + sli;
            g_d = bf2f(delta_b[(row << 11) + d0 + sc]);
            g_u = bf2f(ub[(row << 11) + d0 + sc]);
            g_b = xdbl[(row << 7) + 64 + sc];
            g_c = xdbl[(row << 7) + 80 + sc];
            g_r = bf2f(xrb[(row << 12) + 2048 + d0 + sc]);
        }
        float e_[SCAN_T], f_[SCAN_T], c_[SCAN_T];
        #pragma unroll
        for (int li = 0; li < SCAN_T; ++li) {
            float2 duv = du[cb][li][ch];
            float2 bcv = bc[cb][li][n];
            e_[li] = __expf(duv.x * Aval);
            f_[li] = duv.x * bcv.x * duv.y;
            c_[li] = bcv.y;
        }
        float mysum = 0.f;
        #pragma unroll
        for (int li = 0; li < SCAN_T; ++li) {
            h = fmaf(e_[li], h, f_[li]);
            float pv = h * c_[li];
            pv = DPP_ADD(pv, 0xB1);
            pv = DPP_ADD(pv, 0x4E);
            pv = DPP_ADD(pv, 0x141);
            pv = DPP_ADD(pv, 0x140);
            mysum = (n == li) ? pv : mysum;
        }
        {
            float2 duv = du[cb][n][ch];
            float resv = rs[cb][n][ch];
            float outv = (mysum + duv.y * Dval) * silu_f(resv);
            ysb[((size_t)((b << 10) + l0 + n) << 11) + d0 + ch] = f2bf(outv);
        }
        if (more) {
            du[cb ^ 1][sli][sc] = make_float2(g_d, g_u);
            bc[cb ^ 1][sli][sc] = make_float2(g_b, g_c);
            rs[cb ^ 1][sli][sc] = g_r;
        }
        __syncthreads();
        cb ^= 1;
    }
}

extern "C" void kernel_launch(void* const* d_in, const int* in_sizes, int n_in,
                              void* d_out, int out_size, void* d_ws, size_t ws_size,
                              hipStream_t stream)
{
    const float* x      = (const float*)d_in[0];
    const float* W_in   = (const float*)d_in[1];
    const float* conv_w = (const float*)d_in[2];
    const float* conv_b = (const float*)d_in[3];
    const float* W_x    = (const float*)d_in[4];
    const float* W_dt   = (const float*)d_in[5];
    const float* b_dt   = (const float*)d_in[6];
    const float* A_log  = (const float*)d_in[7];
    const float* Dv     = (const float*)d_in[8];
    const float* W_out  = (const float*)d_in[9];
    float* out = (float*)d_out;

    float* ws    = (float*)d_ws;
    float* xdbl  = ws;                               //   262,144 f [2048][128]
    float* P16   = ws + (size_t)262144;              // 4,194,304 f (16 partials)
    float* P4    = ws + (size_t)4456448;             // 8,388,608 f (4 partials)
    float* stash = ws + (size_t)12845056;            // 1,048,576 f (A_seg,B_seg)
    unsigned short* bfr = (unsigned short*)(ws + (size_t)13893632);
    unsigned short* xb      = bfr;                       // [2048][1024]
    unsigned short* W_inT   = bfr + (size_t)2097152;     // [4096][1024]
    unsigned short* W_xTp   = bfr + (size_t)6291456;     // [128][2048]
    unsigned short* W_dtTp  = bfr + (size_t)6553600;     // [2048][128]
    unsigned short* W_outT  = bfr + (size_t)6815744;     // [1024][2048]
    unsigned short* xrb     = bfr + (size_t)8912896;     // [2048][4096]
    unsigned short* ub      = bfr + (size_t)17301504;    // [2048][2048]
    unsigned short* delta_b = bfr + (size_t)21495808;    // [2048][2048]
    unsigned short* ysb     = bfr + (size_t)25690112;    // [2048][2048]
    unsigned short* xdbl_b  = bfr + (size_t)29884416;    // [2048][128]

    // 1. x -> bf16, W_in -> W_inT
    prep<<<2048, 256, 0, stream>>>(x, W_in, xb, W_inT);
    // 2. GEMM1 (bf16 out) + W_out/W_x/W_dt transposes in one dispatch
    gemm1_fused<<<1536, 256, 0, stream>>>(xb, W_inT, xrb, W_out, W_x, W_dt,
                                          W_outT, W_xTp, W_dtTp);
    // 3. u(bf16) = silu(causal dwconv(xr[:, :2048]))
    conv_silu<<<4096, 256, 0, stream>>>(xrb, conv_w, conv_b, ub);
    // 4. xdbl = u @ W_x  64²-tile split-K=16 (1024 blocks, 4/CU)
    gemm64_bf16<0><<<dim3(2, 32, 16), 256, 0, stream>>>(ub, W_xTp, P16, nullptr, nullptr, 2048, 128, 2048, 128);
    reduce16<<<256, 256, 0, stream>>>(P16, xdbl, xdbl_b);
    // 5. delta(bf16) = softplus(xdbl @ W_dt + b_dt)  64²-tile (1024 blocks)
    gemm64_bf16<3><<<dim3(32, 32, 1), 256, 0, stream>>>(xdbl_b, W_dtTp, nullptr, delta_b, b_dt, 2048, 2048, 128, 128);
    // 6. segmented scan: per-segment maps -> replay (h0 composed inline)
    scan_pass1<<<dim3(128, 2, 8), 256, 0, stream>>>(delta_b, ub, xdbl, A_log, stash);
    scan_pass3<<<dim3(128, 2, 8), 256, 0, stream>>>(delta_b, ub, xdbl, A_log, xrb, stash, Dv, ysb);
    // 7. out = ys @ W_out  128²-tile split-K=4
    gemm_bf16<0><<<dim3(8, 16, 4), 256, 0, stream>>>(ysb, W_outT, P4, nullptr, 2048, 1024, 2048, 512);
    reduce4<<<2048, 256, 0, stream>>>(P4, out);
}